// Round 7
// baseline (451.560 us; speedup 1.0000x reference)
//
#include <hip/hip_runtime.h>
#include <math.h>

#define N_NODES 100000
#define N_EDGES 1600000
#define OUTC 40
#define PAIRS40 20

#define NC 32                       // edge chunks
#define CHUNK (N_EDGES / NC)        // 50000 exact

// histogram pass: 16-bit packed counters, 32768 nodes/range
#define RANGE_H 32768
#define NR_H 4                      // 4*32768 = 131072 >= N
#define NPAD_H (NR_H * RANGE_H)     // 131072

// fill pass: 32-bit position counters, 16384 nodes/range
#define RANGE_F 16384
#define NR_F 7                      // 7*16384 = 114688 >= N

#define SCAN_BLOCK 1024
#define SCAN_NBLK ((N_NODES + SCAN_BLOCK - 1) / SCAN_BLOCK)   // 98

typedef float vf2 __attribute__((ext_vector_type(2)));   // native vector: OK for nontemporal builtins

__device__ inline unsigned pack_bf16x2(float lo, float hi) {
    unsigned a = __float_as_uint(lo), b = __float_as_uint(hi);
    a = (a + 0x7fffu + ((a >> 16) & 1u)) >> 16;
    b = (b + 0x7fffu + ((b >> 16) & 1u)) & 0xffff0000u;
    return a | b;
}
__device__ inline float bf_lo(unsigned u) { return __uint_as_float(u << 16); }
__device__ inline float bf_hi(unsigned u) { return __uint_as_float(u & 0xffff0000u); }

// ---------------- histogram: packed 16-bit LDS counters ----------------
__global__ __launch_bounds__(1024) void k_hist(const int* __restrict__ src,
                                               const int* __restrict__ dst,
                                               int* __restrict__ Hs,
                                               int* __restrict__ Hd) {
    __shared__ unsigned h32[RANGE_H / 2];    // 64 KB, two 16-bit counters per int
    int c = blockIdx.x, r = blockIdx.y;
    const int* a = blockIdx.z ? dst : src;
    int* H = blockIdx.z ? Hd : Hs;
    for (int k = threadIdx.x; k < RANGE_H / 2; k += 1024) h32[k] = 0;
    __syncthreads();
    int r0 = r * RANGE_H;
    int e0 = c * CHUNK, e1 = e0 + CHUNK;
    for (int e = e0 + threadIdx.x; e < e1; e += 1024) {
        unsigned d = (unsigned)(a[e] - r0);
        if (d < RANGE_H) atomicAdd(&h32[d >> 1], 1u << ((d & 1) * 16));
    }
    __syncthreads();
    for (int k = threadIdx.x; k < RANGE_H; k += 1024)
        H[c * NPAD_H + r0 + k] = (int)((h32[k >> 1] >> ((k & 1) * 16)) & 0xffffu);
}

// deg_src = column-sum of Hs; maxdeg
__global__ __launch_bounds__(256) void k_degsrc(const int* __restrict__ Hs,
                                                int* __restrict__ deg_src,
                                                int* __restrict__ maxdeg) {
    int i = blockIdx.x * 256 + threadIdx.x;
    int v = 0;
    if (i < N_NODES) {
        #pragma unroll
        for (int c = 0; c < NC; c++) v += Hs[c * NPAD_H + i];
        deg_src[i] = v;
    }
    int m = v;
    for (int off = 32; off; off >>= 1) m = max(m, __shfl_down(m, off));
    if ((threadIdx.x & 63) == 0) atomicMax(maxdeg, m);
}

// inclusive scan of deg_dst (= column-sum of Hd) -> rowptr[i+1]
__global__ __launch_bounds__(SCAN_BLOCK) void k_scan1(const int* __restrict__ Hd,
                                                      int* __restrict__ rowptr,
                                                      int* __restrict__ blocksum) {
    __shared__ int buf[2][SCAN_BLOCK];
    int t = threadIdx.x;
    int i = blockIdx.x * SCAN_BLOCK + t;
    int v = 0;
    if (i < N_NODES) {
        #pragma unroll
        for (int c = 0; c < NC; c++) v += Hd[c * NPAD_H + i];
    }
    int cur = 0;
    buf[0][t] = v;
    __syncthreads();
    for (int off = 1; off < SCAN_BLOCK; off <<= 1) {
        int nv = buf[cur][t];
        if (t >= off) nv += buf[cur][t - off];
        buf[1 - cur][t] = nv;
        cur = 1 - cur;
        __syncthreads();
    }
    int incl = buf[cur][t];
    if (i < N_NODES) rowptr[i + 1] = incl;
    if (t == SCAN_BLOCK - 1) blocksum[blockIdx.x] = incl;
}

__global__ __launch_bounds__(SCAN_BLOCK) void k_scan2(int* __restrict__ rowptr,
                                                      const int* __restrict__ blocksum) {
    __shared__ int offs[SCAN_NBLK];
    if (threadIdx.x == 0) {
        int run = 0;
        for (int b = 0; b < SCAN_NBLK; b++) { offs[b] = run; run += blocksum[b]; }
        rowptr[0] = 0;
    }
    __syncthreads();
    for (int i = threadIdx.x; i < N_NODES; i += SCAN_BLOCK)
        rowptr[i + 1] += offs[i / SCAN_BLOCK];
}

// Hd[c][d] := rowptr[d] + sum_{c'<c} Hd[c'][d]
__global__ __launch_bounds__(256) void k_basepos(const int* __restrict__ rowptr,
                                                 int* __restrict__ Hd) {
    int i = blockIdx.x * 256 + threadIdx.x;
    if (i >= N_NODES) return;
    int run = rowptr[i];
    #pragma unroll
    for (int c = 0; c < NC; c++) {
        int t = Hd[c * NPAD_H + i];
        Hd[c * NPAD_H + i] = run;
        run += t;
    }
}

// counting-sort fill: LDS position counters, no global atomics
__global__ __launch_bounds__(1024) void k_fill2(const int* __restrict__ src,
                                                const int* __restrict__ dst,
                                                const int* __restrict__ basepos,
                                                int* __restrict__ csr_src) {
    __shared__ int pos[RANGE_F];
    int c = blockIdx.x, r = blockIdx.y;
    int r0 = r * RANGE_F;
    for (int k = threadIdx.x; k < RANGE_F; k += 1024) pos[k] = basepos[c * NPAD_H + r0 + k];
    __syncthreads();
    int e0 = c * CHUNK, e1 = e0 + CHUNK;
    for (int e = e0 + threadIdx.x; e < e1; e += 1024) {
        unsigned d = (unsigned)(dst[e] - r0);
        if (d < RANGE_F) {
            int s = src[e];
            int p = atomicAdd(&pos[d], 1);
            csr_src[p] = s;
        }
    }
}

// ---------------- GEMM 64->64: 32-row tile, thread = 4 rows x 2 cols ----------------
__global__ __launch_bounds__(256) void k_gemm64(const float* __restrict__ h,
                                                const float* __restrict__ W0,
                                                const float* __restrict__ W1,
                                                const float* __restrict__ b,
                                                float2* __restrict__ G02,
                                                unsigned* __restrict__ G1b) {
    __shared__ float2 sw0[64 * 32], sw1[64 * 32];   // 32 KB
    __shared__ float sh[32 * 64];                   // 8 KB
    int t = threadIdx.x;
    const float2* W02 = (const float2*)W0;
    const float2* W12 = (const float2*)W1;
    for (int k = t; k < 64 * 32; k += 256) { sw0[k] = W02[k]; sw1[k] = W12[k]; }
    int i0 = blockIdx.x * 32;    // grid exactly N/32
    const float4* h4 = (const float4*)(h + (size_t)i0 * 64);
    float4* sh4 = (float4*)sh;
    for (int k = t; k < 512; k += 256) sh4[k] = h4[k];
    __syncthreads();
    int c2 = t & 31, rg = t >> 5;          // rows rg, rg+8, rg+16, rg+24
    float2 b2 = ((const float2*)b)[c2];
    float a0x[4], a0y[4], a1x[4], a1y[4];
    #pragma unroll
    for (int p = 0; p < 4; p++) { a0x[p] = b2.x; a0y[p] = b2.y; a1x[p] = 0.f; a1y[p] = 0.f; }
    #pragma unroll
    for (int k = 0; k < 64; k++) {
        float2 w0 = sw0[k * 32 + c2];
        float2 w1 = sw1[k * 32 + c2];
        #pragma unroll
        for (int p = 0; p < 4; p++) {
            float hv = sh[(rg + 8 * p) * 64 + k];
            a0x[p] += hv * w0.x; a0y[p] += hv * w0.y;
            a1x[p] += hv * w1.x; a1y[p] += hv * w1.y;
        }
    }
    #pragma unroll
    for (int p = 0; p < 4; p++) {
        int gi = (i0 + rg + 8 * p) * 32 + c2;
        G02[gi] = make_float2(a0x[p], a0y[p]);
        G1b[gi] = pack_bf16x2(a1x[p], a1y[p]);
    }
}

// ---------------- GEMM 64->40 ----------------
__global__ __launch_bounds__(256) void k_gemm40(const float* __restrict__ h,
                                                const float* __restrict__ W0,
                                                const float* __restrict__ W1,
                                                const float* __restrict__ b,
                                                float2* __restrict__ G02,
                                                unsigned* __restrict__ G1b) {
    __shared__ float2 sw0[64 * PAIRS40], sw1[64 * PAIRS40];   // 20 KB
    __shared__ float sh[32 * 64];                             // 8 KB
    int t = threadIdx.x;
    const float2* W02 = (const float2*)W0;
    const float2* W12 = (const float2*)W1;
    for (int k = t; k < 64 * PAIRS40; k += 256) { sw0[k] = W02[k]; sw1[k] = W12[k]; }
    int i0 = blockIdx.x * 32;
    const float4* h4 = (const float4*)(h + (size_t)i0 * 64);
    float4* sh4 = (float4*)sh;
    for (int k = t; k < 512; k += 256) sh4[k] = h4[k];
    __syncthreads();
    int c2 = t & 31, rg = t >> 5;
    if (c2 >= PAIRS40) return;
    float2 b2 = ((const float2*)b)[c2];
    float a0x[4], a0y[4], a1x[4], a1y[4];
    #pragma unroll
    for (int p = 0; p < 4; p++) { a0x[p] = b2.x; a0y[p] = b2.y; a1x[p] = 0.f; a1y[p] = 0.f; }
    #pragma unroll
    for (int k = 0; k < 64; k++) {
        float2 w0 = sw0[k * PAIRS40 + c2];
        float2 w1 = sw1[k * PAIRS40 + c2];
        #pragma unroll
        for (int p = 0; p < 4; p++) {
            float hv = sh[(rg + 8 * p) * 64 + k];
            a0x[p] += hv * w0.x; a0y[p] += hv * w0.y;
            a1x[p] += hv * w1.x; a1y[p] += hv * w1.y;
        }
    }
    #pragma unroll
    for (int p = 0; p < 4; p++) {
        int gi = (i0 + rg + 8 * p) * PAIRS40 + c2;
        G02[gi] = make_float2(a0x[p], a0y[p]);
        G1b[gi] = pack_bf16x2(a1x[p], a1y[p]);
    }
}

// ---------------- fused SpMM + relu, 64 ch, 4 gathers in flight per lane ----------------
__global__ __launch_bounds__(256, 8) void k_spmm64(const vf2* __restrict__ G02,
                                                   const unsigned* __restrict__ G1b,
                                                   const int* __restrict__ rowptr,
                                                   const int* __restrict__ csr_src,
                                                   const int* __restrict__ deg_src,
                                                   const int* __restrict__ maxdeg,
                                                   vf2* __restrict__ out2) {
    int wave = threadIdx.x >> 6;
    int lane = threadIdx.x & 63;
    int half = lane >> 5, c2 = lane & 31;
    int i = blockIdx.x * 4 + wave;
    float scale = 1.0f / (float)(*maxdeg);
    int e0 = rowptr[i], e1 = rowptr[i + 1];
    float acc0 = 0.f, acc1 = 0.f;
    for (int base = e0; base < e1; base += 64) {
        int n = min(64, e1 - base);
        int idx = (base + lane < e1) ? __builtin_nontemporal_load(&csr_src[base + lane]) : 0;
        int j = 0;
        for (; j + 8 <= n; j += 8) {            // 8 edges per iter, 4 loads in flight
            int s0 = __shfl(idx, j + half);
            int s1 = __shfl(idx, j + 2 + half);
            int s2 = __shfl(idx, j + 4 + half);
            int s3 = __shfl(idx, j + 6 + half);
            unsigned u0 = G1b[s0 * 32 + c2];
            unsigned u1 = G1b[s1 * 32 + c2];
            unsigned u2 = G1b[s2 * 32 + c2];
            unsigned u3 = G1b[s3 * 32 + c2];
            acc0 += (bf_lo(u0) + bf_lo(u1)) + (bf_lo(u2) + bf_lo(u3));
            acc1 += (bf_hi(u0) + bf_hi(u1)) + (bf_hi(u2) + bf_hi(u3));
        }
        for (; j < n; j += 2) {
            int s = __shfl(idx, j + half);
            bool valid = (j + half) < n;
            unsigned u = G1b[s * 32 + c2];
            if (valid) { acc0 += bf_lo(u); acc1 += bf_hi(u); }
        }
    }
    acc0 += __shfl_xor(acc0, 32);
    acc1 += __shfl_xor(acc1, 32);
    if (half == 0) {
        vf2 g0 = __builtin_nontemporal_load(&G02[i * 32 + c2]);
        unsigned ug = G1b[i * 32 + c2];
        float nl = (float)deg_src[i] * scale - 1.0f;
        vf2 v;
        v.x = fmaxf(g0.x + nl * bf_lo(ug) - scale * acc0, 0.f);
        v.y = fmaxf(g0.y + nl * bf_hi(ug) - scale * acc1, 0.f);
        __builtin_nontemporal_store(v, &out2[i * 32 + c2]);
    }
}

// ---------------- fused SpMM + log_softmax, 40 ch ----------------
__global__ __launch_bounds__(256, 8) void k_spmm40(const vf2* __restrict__ G02,
                                                   const unsigned* __restrict__ G1b,
                                                   const int* __restrict__ rowptr,
                                                   const int* __restrict__ csr_src,
                                                   const int* __restrict__ deg_src,
                                                   const int* __restrict__ maxdeg,
                                                   vf2* __restrict__ out2) {
    int wave = threadIdx.x >> 6;
    int lane = threadIdx.x & 63;
    int half = lane >> 5, c2 = lane & 31;
    bool act = c2 < PAIRS40;
    int i = blockIdx.x * 4 + wave;
    float scale = 1.0f / (float)(*maxdeg);
    int e0 = rowptr[i], e1 = rowptr[i + 1];
    float acc0 = 0.f, acc1 = 0.f;
    for (int base = e0; base < e1; base += 64) {
        int n = min(64, e1 - base);
        int idx = (base + lane < e1) ? __builtin_nontemporal_load(&csr_src[base + lane]) : 0;
        int j = 0;
        for (; j + 8 <= n; j += 8) {
            int s0 = __shfl(idx, j + half);
            int s1 = __shfl(idx, j + 2 + half);
            int s2 = __shfl(idx, j + 4 + half);
            int s3 = __shfl(idx, j + 6 + half);
            if (act) {
                unsigned u0 = G1b[s0 * PAIRS40 + c2];
                unsigned u1 = G1b[s1 * PAIRS40 + c2];
                unsigned u2 = G1b[s2 * PAIRS40 + c2];
                unsigned u3 = G1b[s3 * PAIRS40 + c2];
                acc0 += (bf_lo(u0) + bf_lo(u1)) + (bf_lo(u2) + bf_lo(u3));
                acc1 += (bf_hi(u0) + bf_hi(u1)) + (bf_hi(u2) + bf_hi(u3));
            }
        }
        for (; j < n; j += 2) {
            int s = __shfl(idx, j + half);
            bool valid = act && (j + half) < n;
            if (valid) {
                unsigned u = G1b[s * PAIRS40 + c2];
                acc0 += bf_lo(u); acc1 += bf_hi(u);
            }
        }
    }
    acc0 += __shfl_xor(acc0, 32);
    acc1 += __shfl_xor(acc1, 32);
    float vx = 0.f, vy = 0.f;
    if (act) {
        vf2 g0 = __builtin_nontemporal_load(&G02[i * PAIRS40 + c2]);
        unsigned ug = G1b[i * PAIRS40 + c2];
        float nl = (float)deg_src[i] * scale - 1.0f;
        vx = g0.x + nl * bf_lo(ug) - scale * acc0;
        vy = g0.y + nl * bf_hi(ug) - scale * acc1;
    }
    float m = act ? fmaxf(vx, vy) : -INFINITY;
    for (int off = 16; off; off >>= 1) m = fmaxf(m, __shfl_xor(m, off));
    float s = act ? (__expf(vx - m) + __expf(vy - m)) : 0.f;
    for (int off = 16; off; off >>= 1) s += __shfl_xor(s, off);
    float ls = __logf(s);
    if (act && half == 0) {
        vf2 v; v.x = vx - m - ls; v.y = vy - m - ls;
        __builtin_nontemporal_store(v, &out2[i * PAIRS40 + c2]);
    }
}

// ---------------- launch ----------------

extern "C" void kernel_launch(void* const* d_in, const int* in_sizes, int n_in,
                              void* d_out, int out_size, void* d_ws, size_t ws_size,
                              hipStream_t stream) {
    const float* x   = (const float*)d_in[0];
    const int* ei    = (const int*)d_in[1];
    const int* src   = ei;
    const int* dst   = ei + N_EDGES;
    const float* W0_0 = (const float*)d_in[2];
    const float* W1_0 = (const float*)d_in[3];
    const float* b_0  = (const float*)d_in[4];
    const float* W0_1 = (const float*)d_in[5];
    const float* W1_1 = (const float*)d_in[6];
    const float* b_1  = (const float*)d_in[7];
    const float* W0_2 = (const float*)d_in[8];
    const float* W1_2 = (const float*)d_in[9];
    const float* b_2  = (const float*)d_in[10];
    float* outp = (float*)d_out;

    // workspace layout
    int* ip = (int*)d_ws;
    int* deg_src  = ip;                      // N
    int* rowptr   = ip + 100000;             // N+1 (padded to 100032)
    int* blocksum = ip + 200064;             // 128
    int* maxdeg   = ip + 200192;             // 1 (padded to 64)
    int* csr_src  = ip + 200256;             // E
    float* fb = (float*)(ip + 1800256);
    float* hbuf = fb;                        // N*64 fp32
    float* G0   = fb + 6400000;              // region (also Hs: NC*NPAD_H=4.19M ints)
    float* G1   = fb + 12800000;             // region (G1b: N*32 uints; also Hd)
    int* Hs = (int*)G0;
    int* Hd = (int*)G1;
    float2* G02 = (float2*)G0;
    unsigned* G1b = (unsigned*)G1;

    (void)hipMemsetAsync(maxdeg, 0, sizeof(int), stream);

    k_hist<<<dim3(NC, NR_H, 2), 1024, 0, stream>>>(src, dst, Hs, Hd);
    k_degsrc<<<(N_NODES + 255) / 256, 256, 0, stream>>>(Hs, deg_src, maxdeg);
    k_scan1<<<SCAN_NBLK, SCAN_BLOCK, 0, stream>>>(Hd, rowptr, blocksum);
    k_scan2<<<1, SCAN_BLOCK, 0, stream>>>(rowptr, blocksum);
    k_basepos<<<(N_NODES + 255) / 256, 256, 0, stream>>>(rowptr, Hd);
    k_fill2<<<dim3(NC, NR_F), 1024, 0, stream>>>(src, dst, Hd, csr_src);

    const int GN = N_NODES / 4;    // 25000, exact
    const int GG = N_NODES / 32;   // 3125, exact

    // layer 0: x -> hbuf
    k_gemm64<<<GG, 256, 0, stream>>>(x, W0_0, W1_0, b_0, G02, G1b);
    k_spmm64<<<GN, 256, 0, stream>>>((const vf2*)G02, G1b, rowptr, csr_src, deg_src, maxdeg, (vf2*)hbuf);
    // layer 1: hbuf -> hbuf
    k_gemm64<<<GG, 256, 0, stream>>>(hbuf, W0_1, W1_1, b_1, G02, G1b);
    k_spmm64<<<GN, 256, 0, stream>>>((const vf2*)G02, G1b, rowptr, csr_src, deg_src, maxdeg, (vf2*)hbuf);
    // layer 2: hbuf -> out (40 ch + log_softmax)
    k_gemm40<<<GG, 256, 0, stream>>>(hbuf, W0_2, W1_2, b_2, G02, G1b);
    k_spmm40<<<GN, 256, 0, stream>>>((const vf2*)G02, G1b, rowptr, csr_src, deg_src, maxdeg, (vf2*)outp);
}

// Round 8
// 413.406 us; speedup vs baseline: 1.0923x; 1.0923x over previous
//
#include <hip/hip_runtime.h>
#include <math.h>

#define N_NODES 100000
#define N_EDGES 1600000
#define OUTC 40
#define PAIRS40 20

#define NC 32                       // edge chunks
#define CHUNK (N_EDGES / NC)        // 50000 exact

// histogram pass: 16-bit packed counters, 32768 nodes/range
#define RANGE_H 32768
#define NR_H 4                      // 4*32768 = 131072 >= N
#define NPAD_H (NR_H * RANGE_H)     // 131072

// fill pass: 32-bit position counters, 16384 nodes/range
#define RANGE_F 16384
#define NR_F 7                      // 7*16384 = 114688 >= N

#define SCAN_BLOCK 1024
#define SCAN_NBLK ((N_NODES + SCAN_BLOCK - 1) / SCAN_BLOCK)   // 98

typedef float vf2 __attribute__((ext_vector_type(2)));

// ---------------- histogram: packed 16-bit LDS counters ----------------
__global__ __launch_bounds__(1024) void k_hist(const int* __restrict__ src,
                                               const int* __restrict__ dst,
                                               int* __restrict__ Hs,
                                               int* __restrict__ Hd) {
    __shared__ unsigned h32[RANGE_H / 2];    // 64 KB, two 16-bit counters per int
    int c = blockIdx.x, r = blockIdx.y;
    const int* a = blockIdx.z ? dst : src;
    int* H = blockIdx.z ? Hd : Hs;
    for (int k = threadIdx.x; k < RANGE_H / 2; k += 1024) h32[k] = 0;
    __syncthreads();
    int r0 = r * RANGE_H;
    int e0 = c * CHUNK, e1 = e0 + CHUNK;
    for (int e = e0 + threadIdx.x; e < e1; e += 1024) {
        unsigned d = (unsigned)(a[e] - r0);
        if (d < RANGE_H) atomicAdd(&h32[d >> 1], 1u << ((d & 1) * 16));
    }
    __syncthreads();
    for (int k = threadIdx.x; k < RANGE_H; k += 1024)
        H[c * NPAD_H + r0 + k] = (int)((h32[k >> 1] >> ((k & 1) * 16)) & 0xffffu);
}

// deg_src = column-sum of Hs; maxdeg
__global__ __launch_bounds__(256) void k_degsrc(const int* __restrict__ Hs,
                                                int* __restrict__ deg_src,
                                                int* __restrict__ maxdeg) {
    int i = blockIdx.x * 256 + threadIdx.x;
    int v = 0;
    if (i < N_NODES) {
        #pragma unroll
        for (int c = 0; c < NC; c++) v += Hs[c * NPAD_H + i];
        deg_src[i] = v;
    }
    int m = v;
    for (int off = 32; off; off >>= 1) m = max(m, __shfl_down(m, off));
    if ((threadIdx.x & 63) == 0) atomicMax(maxdeg, m);
}

// inclusive scan of deg_dst (= column-sum of Hd) -> rowptr[i+1]
__global__ __launch_bounds__(SCAN_BLOCK) void k_scan1(const int* __restrict__ Hd,
                                                      int* __restrict__ rowptr,
                                                      int* __restrict__ blocksum) {
    __shared__ int buf[2][SCAN_BLOCK];
    int t = threadIdx.x;
    int i = blockIdx.x * SCAN_BLOCK + t;
    int v = 0;
    if (i < N_NODES) {
        #pragma unroll
        for (int c = 0; c < NC; c++) v += Hd[c * NPAD_H + i];
    }
    int cur = 0;
    buf[0][t] = v;
    __syncthreads();
    for (int off = 1; off < SCAN_BLOCK; off <<= 1) {
        int nv = buf[cur][t];
        if (t >= off) nv += buf[cur][t - off];
        buf[1 - cur][t] = nv;
        cur = 1 - cur;
        __syncthreads();
    }
    int incl = buf[cur][t];
    if (i < N_NODES) rowptr[i + 1] = incl;
    if (t == SCAN_BLOCK - 1) blocksum[blockIdx.x] = incl;
}

__global__ __launch_bounds__(SCAN_BLOCK) void k_scan2(int* __restrict__ rowptr,
                                                      const int* __restrict__ blocksum) {
    __shared__ int offs[SCAN_NBLK];
    if (threadIdx.x == 0) {
        int run = 0;
        for (int b = 0; b < SCAN_NBLK; b++) { offs[b] = run; run += blocksum[b]; }
        rowptr[0] = 0;
    }
    __syncthreads();
    for (int i = threadIdx.x; i < N_NODES; i += SCAN_BLOCK)
        rowptr[i + 1] += offs[i / SCAN_BLOCK];
}

// Hd[c][d] := rowptr[d] + sum_{c'<c} Hd[c'][d]
__global__ __launch_bounds__(256) void k_basepos(const int* __restrict__ rowptr,
                                                 int* __restrict__ Hd) {
    int i = blockIdx.x * 256 + threadIdx.x;
    if (i >= N_NODES) return;
    int run = rowptr[i];
    #pragma unroll
    for (int c = 0; c < NC; c++) {
        int t = Hd[c * NPAD_H + i];
        Hd[c * NPAD_H + i] = run;
        run += t;
    }
}

// counting-sort fill: LDS position counters, no global atomics
__global__ __launch_bounds__(1024) void k_fill2(const int* __restrict__ src,
                                                const int* __restrict__ dst,
                                                const int* __restrict__ basepos,
                                                int* __restrict__ csr_src) {
    __shared__ int pos[RANGE_F];
    int c = blockIdx.x, r = blockIdx.y;
    int r0 = r * RANGE_F;
    for (int k = threadIdx.x; k < RANGE_F; k += 1024) pos[k] = basepos[c * NPAD_H + r0 + k];
    __syncthreads();
    int e0 = c * CHUNK, e1 = e0 + CHUNK;
    for (int e = e0 + threadIdx.x; e < e1; e += 1024) {
        unsigned d = (unsigned)(dst[e] - r0);
        if (d < RANGE_F) {
            int s = src[e];
            int p = atomicAdd(&pos[d], 1);
            csr_src[p] = s;
        }
    }
}

// ---------------- GEMM 64->64: G0' = h@W0 + b + nl*(h@W1) fp32; G1 = fp8(h@W1) ----------------
__global__ __launch_bounds__(256) void k_gemm64(const float* __restrict__ h,
                                                const float* __restrict__ W0,
                                                const float* __restrict__ W1,
                                                const float* __restrict__ b,
                                                const int* __restrict__ deg_src,
                                                const int* __restrict__ maxdeg,
                                                float2* __restrict__ G02,
                                                unsigned short* __restrict__ G1f8) {
    __shared__ float2 sw0[64 * 32], sw1[64 * 32];   // 32 KB
    __shared__ float sh[32 * 64];                   // 8 KB
    int t = threadIdx.x;
    const float2* W02 = (const float2*)W0;
    const float2* W12 = (const float2*)W1;
    for (int k = t; k < 64 * 32; k += 256) { sw0[k] = W02[k]; sw1[k] = W12[k]; }
    int i0 = blockIdx.x * 32;    // grid exactly N/32
    const float4* h4 = (const float4*)(h + (size_t)i0 * 64);
    float4* sh4 = (float4*)sh;
    for (int k = t; k < 512; k += 256) sh4[k] = h4[k];
    __syncthreads();
    int c2 = t & 31, rg = t >> 5;          // rows rg, rg+8, rg+16, rg+24
    float scale = 1.0f / (float)(*maxdeg);
    float2 b2 = ((const float2*)b)[c2];
    float a0x[4], a0y[4], a1x[4], a1y[4];
    #pragma unroll
    for (int p = 0; p < 4; p++) { a0x[p] = b2.x; a0y[p] = b2.y; a1x[p] = 0.f; a1y[p] = 0.f; }
    #pragma unroll
    for (int k = 0; k < 64; k++) {
        float2 w0 = sw0[k * 32 + c2];
        float2 w1 = sw1[k * 32 + c2];
        #pragma unroll
        for (int p = 0; p < 4; p++) {
            float hv = sh[(rg + 8 * p) * 64 + k];
            a0x[p] += hv * w0.x; a0y[p] += hv * w0.y;
            a1x[p] += hv * w1.x; a1y[p] += hv * w1.y;
        }
    }
    #pragma unroll
    for (int p = 0; p < 4; p++) {
        int row = i0 + rg + 8 * p;
        float nl = (float)deg_src[row] * scale - 1.0f;
        G02[row * 32 + c2] = make_float2(a0x[p] + nl * a1x[p], a0y[p] + nl * a1y[p]);
        int pk = __builtin_amdgcn_cvt_pk_fp8_f32(a1x[p], a1y[p], 0, false);
        G1f8[row * 32 + c2] = (unsigned short)(pk & 0xffff);
    }
}

// ---------------- GEMM 64->40 ----------------
__global__ __launch_bounds__(256) void k_gemm40(const float* __restrict__ h,
                                                const float* __restrict__ W0,
                                                const float* __restrict__ W1,
                                                const float* __restrict__ b,
                                                const int* __restrict__ deg_src,
                                                const int* __restrict__ maxdeg,
                                                float2* __restrict__ G02,
                                                unsigned short* __restrict__ G1f8) {
    __shared__ float2 sw0[64 * PAIRS40], sw1[64 * PAIRS40];   // 20 KB
    __shared__ float sh[32 * 64];                             // 8 KB
    int t = threadIdx.x;
    const float2* W02 = (const float2*)W0;
    const float2* W12 = (const float2*)W1;
    for (int k = t; k < 64 * PAIRS40; k += 256) { sw0[k] = W02[k]; sw1[k] = W12[k]; }
    int i0 = blockIdx.x * 32;
    const float4* h4 = (const float4*)(h + (size_t)i0 * 64);
    float4* sh4 = (float4*)sh;
    for (int k = t; k < 512; k += 256) sh4[k] = h4[k];
    __syncthreads();
    int c2 = t & 31, rg = t >> 5;
    if (c2 >= PAIRS40) return;
    float scale = 1.0f / (float)(*maxdeg);
    float2 b2 = ((const float2*)b)[c2];
    float a0x[4], a0y[4], a1x[4], a1y[4];
    #pragma unroll
    for (int p = 0; p < 4; p++) { a0x[p] = b2.x; a0y[p] = b2.y; a1x[p] = 0.f; a1y[p] = 0.f; }
    #pragma unroll
    for (int k = 0; k < 64; k++) {
        float2 w0 = sw0[k * PAIRS40 + c2];
        float2 w1 = sw1[k * PAIRS40 + c2];
        #pragma unroll
        for (int p = 0; p < 4; p++) {
            float hv = sh[(rg + 8 * p) * 64 + k];
            a0x[p] += hv * w0.x; a0y[p] += hv * w0.y;
            a1x[p] += hv * w1.x; a1y[p] += hv * w1.y;
        }
    }
    #pragma unroll
    for (int p = 0; p < 4; p++) {
        int row = i0 + rg + 8 * p;
        float nl = (float)deg_src[row] * scale - 1.0f;
        G02[row * PAIRS40 + c2] = make_float2(a0x[p] + nl * a1x[p], a0y[p] + nl * a1y[p]);
        int pk = __builtin_amdgcn_cvt_pk_fp8_f32(a1x[p], a1y[p], 0, false);
        G1f8[row * PAIRS40 + c2] = (unsigned short)(pk & 0xffff);
    }
}

// ---------------- fused SpMM + relu, 64 ch fp8 gathers ----------------
// wave = node; lane: slot = lane>>3 (edge), ch = lane&7 (8-channel chunk)
// out[i] = relu( G0'[i] - scale * sum_e fp8(G1[src_e]) )
__global__ __launch_bounds__(256) void k_spmm64(const float* __restrict__ G0p,
                                               const unsigned char* __restrict__ g1,
                                               const int* __restrict__ rowptr,
                                               const int* __restrict__ csr_src,
                                               const int* __restrict__ maxdeg,
                                               float* __restrict__ out) {
    int wave = threadIdx.x >> 6;
    int lane = threadIdx.x & 63;
    int slot = lane >> 3, ch = lane & 7;
    int i = blockIdx.x * 4 + wave;
    float scale = 1.0f / (float)(*maxdeg);
    int e0 = rowptr[i], e1 = rowptr[i + 1];
    vf2 acc[4];
    acc[0] = 0.f; acc[1] = 0.f; acc[2] = 0.f; acc[3] = 0.f;
    for (int base = e0; base < e1; base += 64) {
        int nb = min(64, e1 - base);
        int idx = (base + lane < e1) ? csr_src[base + lane] : 0;
        int j = 0;
        for (; j + 16 <= nb; j += 16) {      // 16 edges per iter, 2 loads in flight
            int sA = __shfl(idx, j + slot);
            int sB = __shfl(idx, j + 8 + slot);
            uint2 uA = ((const uint2*)(g1 + (size_t)sA * 64))[ch];
            uint2 uB = ((const uint2*)(g1 + (size_t)sB * 64))[ch];
            acc[0] += __builtin_amdgcn_cvt_pk_f32_fp8((int)uA.x, false);
            acc[1] += __builtin_amdgcn_cvt_pk_f32_fp8((int)uA.x, true);
            acc[2] += __builtin_amdgcn_cvt_pk_f32_fp8((int)uA.y, false);
            acc[3] += __builtin_amdgcn_cvt_pk_f32_fp8((int)uA.y, true);
            acc[0] += __builtin_amdgcn_cvt_pk_f32_fp8((int)uB.x, false);
            acc[1] += __builtin_amdgcn_cvt_pk_f32_fp8((int)uB.x, true);
            acc[2] += __builtin_amdgcn_cvt_pk_f32_fp8((int)uB.y, false);
            acc[3] += __builtin_amdgcn_cvt_pk_f32_fp8((int)uB.y, true);
        }
        for (; j < nb; j += 8) {             // tail: 8 edges per iter
            int gid = j + slot;
            int s = __shfl(idx, gid);
            if (gid < nb) {
                uint2 u = ((const uint2*)(g1 + (size_t)s * 64))[ch];
                acc[0] += __builtin_amdgcn_cvt_pk_f32_fp8((int)u.x, false);
                acc[1] += __builtin_amdgcn_cvt_pk_f32_fp8((int)u.x, true);
                acc[2] += __builtin_amdgcn_cvt_pk_f32_fp8((int)u.y, false);
                acc[3] += __builtin_amdgcn_cvt_pk_f32_fp8((int)u.y, true);
            }
        }
    }
    // reduce over slots (lane bits 3..5)
    #pragma unroll
    for (int off = 8; off <= 32; off <<= 1) {
        #pragma unroll
        for (int q = 0; q < 4; q++) {
            acc[q].x += __shfl_xor(acc[q].x, off);
            acc[q].y += __shfl_xor(acc[q].y, off);
        }
    }
    if (slot == 0) {
        const float4* g04 = (const float4*)(G0p + (size_t)i * 64);
        float4 gA = g04[ch * 2], gB = g04[ch * 2 + 1];
        float4 oA, oB;
        oA.x = fmaxf(gA.x - scale * acc[0].x, 0.f);
        oA.y = fmaxf(gA.y - scale * acc[0].y, 0.f);
        oA.z = fmaxf(gA.z - scale * acc[1].x, 0.f);
        oA.w = fmaxf(gA.w - scale * acc[1].y, 0.f);
        oB.x = fmaxf(gB.x - scale * acc[2].x, 0.f);
        oB.y = fmaxf(gB.y - scale * acc[2].y, 0.f);
        oB.z = fmaxf(gB.z - scale * acc[3].x, 0.f);
        oB.w = fmaxf(gB.w - scale * acc[3].y, 0.f);
        float4* o4 = (float4*)(out + (size_t)i * 64);
        o4[ch * 2] = oA;
        o4[ch * 2 + 1] = oB;
    }
}

// ---------------- fused SpMM + log_softmax, 40 ch fp8 gathers (stride 40 B, L2-resident) ----------------
__global__ __launch_bounds__(256) void k_spmm40(const float* __restrict__ G0p,
                                               const unsigned char* __restrict__ g1,
                                               const int* __restrict__ rowptr,
                                               const int* __restrict__ csr_src,
                                               const int* __restrict__ maxdeg,
                                               float* __restrict__ out) {
    int wave = threadIdx.x >> 6;
    int lane = threadIdx.x & 63;
    int slot = lane >> 3, ch = lane & 7;
    bool act = ch < 5;                       // 5 chunks * 8 = 40 channels
    int i = blockIdx.x * 4 + wave;
    float scale = 1.0f / (float)(*maxdeg);
    int e0 = rowptr[i], e1 = rowptr[i + 1];
    vf2 acc[4];
    acc[0] = 0.f; acc[1] = 0.f; acc[2] = 0.f; acc[3] = 0.f;
    for (int base = e0; base < e1; base += 64) {
        int nb = min(64, e1 - base);
        int idx = (base + lane < e1) ? csr_src[base + lane] : 0;
        int j = 0;
        for (; j + 16 <= nb; j += 16) {
            int sA = __shfl(idx, j + slot);
            int sB = __shfl(idx, j + 8 + slot);
            if (act) {
                uint2 uA = ((const uint2*)(g1 + (size_t)sA * 40))[ch];
                uint2 uB = ((const uint2*)(g1 + (size_t)sB * 40))[ch];
                acc[0] += __builtin_amdgcn_cvt_pk_f32_fp8((int)uA.x, false);
                acc[1] += __builtin_amdgcn_cvt_pk_f32_fp8((int)uA.x, true);
                acc[2] += __builtin_amdgcn_cvt_pk_f32_fp8((int)uA.y, false);
                acc[3] += __builtin_amdgcn_cvt_pk_f32_fp8((int)uA.y, true);
                acc[0] += __builtin_amdgcn_cvt_pk_f32_fp8((int)uB.x, false);
                acc[1] += __builtin_amdgcn_cvt_pk_f32_fp8((int)uB.x, true);
                acc[2] += __builtin_amdgcn_cvt_pk_f32_fp8((int)uB.y, false);
                acc[3] += __builtin_amdgcn_cvt_pk_f32_fp8((int)uB.y, true);
            }
        }
        for (; j < nb; j += 8) {
            int gid = j + slot;
            int s = __shfl(idx, gid);
            if (act && gid < nb) {
                uint2 u = ((const uint2*)(g1 + (size_t)s * 40))[ch];
                acc[0] += __builtin_amdgcn_cvt_pk_f32_fp8((int)u.x, false);
                acc[1] += __builtin_amdgcn_cvt_pk_f32_fp8((int)u.x, true);
                acc[2] += __builtin_amdgcn_cvt_pk_f32_fp8((int)u.y, false);
                acc[3] += __builtin_amdgcn_cvt_pk_f32_fp8((int)u.y, true);
            }
        }
    }
    #pragma unroll
    for (int off = 8; off <= 32; off <<= 1) {
        #pragma unroll
        for (int q = 0; q < 4; q++) {
            acc[q].x += __shfl_xor(acc[q].x, off);
            acc[q].y += __shfl_xor(acc[q].y, off);
        }
    }
    // epilogue: lanes 0..4 hold the 40 values (8 each); log_softmax over group of 8 lanes
    float v[8];
    bool ep = (slot == 0) && act;
    float m = -INFINITY;
    if (ep) {
        const float4* g04 = (const float4*)(G0p + (size_t)i * 40);
        float4 gA = g04[ch * 2], gB = g04[ch * 2 + 1];
        v[0] = gA.x - scale * acc[0].x;
        v[1] = gA.y - scale * acc[0].y;
        v[2] = gA.z - scale * acc[1].x;
        v[3] = gA.w - scale * acc[1].y;
        v[4] = gB.x - scale * acc[2].x;
        v[5] = gB.y - scale * acc[2].y;
        v[6] = gB.z - scale * acc[3].x;
        v[7] = gB.w - scale * acc[3].y;
        #pragma unroll
        for (int q = 0; q < 8; q++) m = fmaxf(m, v[q]);
    }
    m = fmaxf(m, __shfl_xor(m, 1));
    m = fmaxf(m, __shfl_xor(m, 2));
    m = fmaxf(m, __shfl_xor(m, 4));
    float s = 0.f;
    if (ep) {
        #pragma unroll
        for (int q = 0; q < 8; q++) s += __expf(v[q] - m);
    }
    s += __shfl_xor(s, 1);
    s += __shfl_xor(s, 2);
    s += __shfl_xor(s, 4);
    float ls = __logf(s);
    if (ep) {
        float4 oA, oB;
        oA.x = v[0] - m - ls; oA.y = v[1] - m - ls; oA.z = v[2] - m - ls; oA.w = v[3] - m - ls;
        oB.x = v[4] - m - ls; oB.y = v[5] - m - ls; oB.z = v[6] - m - ls; oB.w = v[7] - m - ls;
        float4* o4 = (float4*)(out + (size_t)i * 40);
        o4[ch * 2] = oA;
        o4[ch * 2 + 1] = oB;
    }
}

// ---------------- launch ----------------

extern "C" void kernel_launch(void* const* d_in, const int* in_sizes, int n_in,
                              void* d_out, int out_size, void* d_ws, size_t ws_size,
                              hipStream_t stream) {
    const float* x   = (const float*)d_in[0];
    const int* ei    = (const int*)d_in[1];
    const int* src   = ei;
    const int* dst   = ei + N_EDGES;
    const float* W0_0 = (const float*)d_in[2];
    const float* W1_0 = (const float*)d_in[3];
    const float* b_0  = (const float*)d_in[4];
    const float* W0_1 = (const float*)d_in[5];
    const float* W1_1 = (const float*)d_in[6];
    const float* b_1  = (const float*)d_in[7];
    const float* W0_2 = (const float*)d_in[8];
    const float* W1_2 = (const float*)d_in[9];
    const float* b_2  = (const float*)d_in[10];
    float* outp = (float*)d_out;

    // workspace layout
    int* ip = (int*)d_ws;
    int* deg_src  = ip;                      // N
    int* rowptr   = ip + 100000;             // N+1 (padded to 100032)
    int* blocksum = ip + 200064;             // 128
    int* maxdeg   = ip + 200192;             // 1 (padded to 64)
    int* csr_src  = ip + 200256;             // E
    float* fb = (float*)(ip + 1800256);
    float* hbuf = fb;                        // N*64 fp32
    float* G0   = fb + 6400000;              // region (also Hs: NC*NPAD_H=4.19M ints)
    float* G1   = fb + 12800000;             // region (G1f8: N*64B; also Hd: 16.8MB)
    int* Hs = (int*)G0;
    int* Hd = (int*)G1;
    float2* G02 = (float2*)G0;
    unsigned short* G1f8 = (unsigned short*)G1;

    (void)hipMemsetAsync(maxdeg, 0, sizeof(int), stream);

    k_hist<<<dim3(NC, NR_H, 2), 1024, 0, stream>>>(src, dst, Hs, Hd);
    k_degsrc<<<(N_NODES + 255) / 256, 256, 0, stream>>>(Hs, deg_src, maxdeg);
    k_scan1<<<SCAN_NBLK, SCAN_BLOCK, 0, stream>>>(Hd, rowptr, blocksum);
    k_scan2<<<1, SCAN_BLOCK, 0, stream>>>(rowptr, blocksum);
    k_basepos<<<(N_NODES + 255) / 256, 256, 0, stream>>>(rowptr, Hd);
    k_fill2<<<dim3(NC, NR_F), 1024, 0, stream>>>(src, dst, Hd, csr_src);

    const int GN = N_NODES / 4;    // 25000, exact
    const int GG = N_NODES / 32;   // 3125, exact

    // layer 0: x -> hbuf
    k_gemm64<<<GG, 256, 0, stream>>>(x, W0_0, W1_0, b_0, deg_src, maxdeg, G02, G1f8);
    k_spmm64<<<GN, 256, 0, stream>>>(G0, (const unsigned char*)G1f8, rowptr, csr_src, maxdeg, hbuf);
    // layer 1: hbuf -> hbuf
    k_gemm64<<<GG, 256, 0, stream>>>(hbuf, W0_1, W1_1, b_1, deg_src, maxdeg, G02, G1f8);
    k_spmm64<<<GN, 256, 0, stream>>>(G0, (const unsigned char*)G1f8, rowptr, csr_src, maxdeg, hbuf);
    // layer 2: hbuf -> out (40 ch + log_softmax), G1 stride 40 B (4 MB, L2-resident)
    k_gemm40<<<GG, 256, 0, stream>>>(hbuf, W0_2, W1_2, b_2, deg_src, maxdeg, G02, G1f8);
    k_spmm40<<<GN, 256, 0, stream>>>(G0, (const unsigned char*)G1f8, rowptr, csr_src, maxdeg, outp);
}

// Round 9
// 386.140 us; speedup vs baseline: 1.1694x; 1.0706x over previous
//
#include <hip/hip_runtime.h>
#include <math.h>

#define N_NODES 100000
#define N_EDGES 1600000
#define OUTC 40
#define PAIRS40 20

#define NC 32                       // edge chunks
#define CHUNK (N_EDGES / NC)        // 50000 exact

// histogram pass: 16-bit packed counters, 32768 nodes/range
#define RANGE_H 32768
#define NR_H 4                      // 4*32768 = 131072 >= N
#define NPAD_H (NR_H * RANGE_H)     // 131072

// fill pass: 32-bit position counters, 16384 nodes/range
#define RANGE_F 16384
#define NR_F 7                      // 7*16384 = 114688 >= N

#define SCAN_BLOCK 1024
#define SCAN_NBLK ((N_NODES + SCAN_BLOCK - 1) / SCAN_BLOCK)   // 98

typedef float vf2 __attribute__((ext_vector_type(2)));

// ---------------- histogram: packed 16-bit LDS counters ----------------
__global__ __launch_bounds__(1024) void k_hist(const int* __restrict__ src,
                                               const int* __restrict__ dst,
                                               int* __restrict__ Hs,
                                               int* __restrict__ Hd) {
    __shared__ unsigned h32[RANGE_H / 2];    // 64 KB, two 16-bit counters per int
    int c = blockIdx.x, r = blockIdx.y;
    const int* a = blockIdx.z ? dst : src;
    int* H = blockIdx.z ? Hd : Hs;
    for (int k = threadIdx.x; k < RANGE_H / 2; k += 1024) h32[k] = 0;
    __syncthreads();
    int r0 = r * RANGE_H;
    int e0 = c * CHUNK, e1 = e0 + CHUNK;
    for (int e = e0 + threadIdx.x; e < e1; e += 1024) {
        unsigned d = (unsigned)(a[e] - r0);
        if (d < RANGE_H) atomicAdd(&h32[d >> 1], 1u << ((d & 1) * 16));
    }
    __syncthreads();
    for (int k = threadIdx.x; k < RANGE_H; k += 1024)
        H[c * NPAD_H + r0 + k] = (int)((h32[k >> 1] >> ((k & 1) * 16)) & 0xffffu);
}

// deg_src = column-sum of Hs; maxdeg
__global__ __launch_bounds__(256) void k_degsrc(const int* __restrict__ Hs,
                                                int* __restrict__ deg_src,
                                                int* __restrict__ maxdeg) {
    int i = blockIdx.x * 256 + threadIdx.x;
    int v = 0;
    if (i < N_NODES) {
        #pragma unroll
        for (int c = 0; c < NC; c++) v += Hs[c * NPAD_H + i];
        deg_src[i] = v;
    }
    int m = v;
    for (int off = 32; off; off >>= 1) m = max(m, __shfl_down(m, off));
    if ((threadIdx.x & 63) == 0) atomicMax(maxdeg, m);
}

// inclusive scan of deg_dst (= column-sum of Hd) -> rowptr[i+1]
__global__ __launch_bounds__(SCAN_BLOCK) void k_scan1(const int* __restrict__ Hd,
                                                      int* __restrict__ rowptr,
                                                      int* __restrict__ blocksum) {
    __shared__ int buf[2][SCAN_BLOCK];
    int t = threadIdx.x;
    int i = blockIdx.x * SCAN_BLOCK + t;
    int v = 0;
    if (i < N_NODES) {
        #pragma unroll
        for (int c = 0; c < NC; c++) v += Hd[c * NPAD_H + i];
    }
    int cur = 0;
    buf[0][t] = v;
    __syncthreads();
    for (int off = 1; off < SCAN_BLOCK; off <<= 1) {
        int nv = buf[cur][t];
        if (t >= off) nv += buf[cur][t - off];
        buf[1 - cur][t] = nv;
        cur = 1 - cur;
        __syncthreads();
    }
    int incl = buf[cur][t];
    if (i < N_NODES) rowptr[i + 1] = incl;
    if (t == SCAN_BLOCK - 1) blocksum[blockIdx.x] = incl;
}

__global__ __launch_bounds__(SCAN_BLOCK) void k_scan2(int* __restrict__ rowptr,
                                                      const int* __restrict__ blocksum) {
    __shared__ int offs[SCAN_NBLK];
    if (threadIdx.x == 0) {
        int run = 0;
        for (int b = 0; b < SCAN_NBLK; b++) { offs[b] = run; run += blocksum[b]; }
        rowptr[0] = 0;
    }
    __syncthreads();
    for (int i = threadIdx.x; i < N_NODES; i += SCAN_BLOCK)
        rowptr[i + 1] += offs[i / SCAN_BLOCK];
}

// Hd[c][d] := rowptr[d] + sum_{c'<c} Hd[c'][d]
__global__ __launch_bounds__(256) void k_basepos(const int* __restrict__ rowptr,
                                                 int* __restrict__ Hd) {
    int i = blockIdx.x * 256 + threadIdx.x;
    if (i >= N_NODES) return;
    int run = rowptr[i];
    #pragma unroll
    for (int c = 0; c < NC; c++) {
        int t = Hd[c * NPAD_H + i];
        Hd[c * NPAD_H + i] = run;
        run += t;
    }
}

// counting-sort fill: LDS position counters, no global atomics
__global__ __launch_bounds__(1024) void k_fill2(const int* __restrict__ src,
                                                const int* __restrict__ dst,
                                                const int* __restrict__ basepos,
                                                int* __restrict__ csr_src) {
    __shared__ int pos[RANGE_F];
    int c = blockIdx.x, r = blockIdx.y;
    int r0 = r * RANGE_F;
    for (int k = threadIdx.x; k < RANGE_F; k += 1024) pos[k] = basepos[c * NPAD_H + r0 + k];
    __syncthreads();
    int e0 = c * CHUNK, e1 = e0 + CHUNK;
    for (int e = e0 + threadIdx.x; e < e1; e += 1024) {
        unsigned d = (unsigned)(dst[e] - r0);
        if (d < RANGE_F) {
            int s = src[e];
            int p = atomicAdd(&pos[d], 1);
            csr_src[p] = s;
        }
    }
}

// ---------------- GEMM 64->64: G0' = h@W0 + b + nl*(h@W1) fp32; G1 = fp8(h@W1) ----------------
__global__ __launch_bounds__(256) void k_gemm64(const float* __restrict__ h,
                                                const float* __restrict__ W0,
                                                const float* __restrict__ W1,
                                                const float* __restrict__ b,
                                                const int* __restrict__ deg_src,
                                                const int* __restrict__ maxdeg,
                                                float2* __restrict__ G02,
                                                unsigned short* __restrict__ G1f8) {
    __shared__ float2 sw0[64 * 32], sw1[64 * 32];   // 32 KB
    __shared__ float sh[32 * 64];                   // 8 KB
    int t = threadIdx.x;
    const float2* W02 = (const float2*)W0;
    const float2* W12 = (const float2*)W1;
    for (int k = t; k < 64 * 32; k += 256) { sw0[k] = W02[k]; sw1[k] = W12[k]; }
    int i0 = blockIdx.x * 32;    // grid exactly N/32
    const float4* h4 = (const float4*)(h + (size_t)i0 * 64);
    float4* sh4 = (float4*)sh;
    for (int k = t; k < 512; k += 256) sh4[k] = h4[k];
    __syncthreads();
    int c2 = t & 31, rg = t >> 5;          // rows rg, rg+8, rg+16, rg+24
    float scale = 1.0f / (float)(*maxdeg);
    float2 b2 = ((const float2*)b)[c2];
    float a0x[4], a0y[4], a1x[4], a1y[4];
    #pragma unroll
    for (int p = 0; p < 4; p++) { a0x[p] = b2.x; a0y[p] = b2.y; a1x[p] = 0.f; a1y[p] = 0.f; }
    #pragma unroll
    for (int k = 0; k < 64; k++) {
        float2 w0 = sw0[k * 32 + c2];
        float2 w1 = sw1[k * 32 + c2];
        #pragma unroll
        for (int p = 0; p < 4; p++) {
            float hv = sh[(rg + 8 * p) * 64 + k];
            a0x[p] += hv * w0.x; a0y[p] += hv * w0.y;
            a1x[p] += hv * w1.x; a1y[p] += hv * w1.y;
        }
    }
    #pragma unroll
    for (int p = 0; p < 4; p++) {
        int row = i0 + rg + 8 * p;
        float nl = (float)deg_src[row] * scale - 1.0f;
        G02[row * 32 + c2] = make_float2(a0x[p] + nl * a1x[p], a0y[p] + nl * a1y[p]);
        int pk = __builtin_amdgcn_cvt_pk_fp8_f32(a1x[p], a1y[p], 0, false);
        G1f8[row * 32 + c2] = (unsigned short)(pk & 0xffff);
    }
}

// ---------------- GEMM 64->40 ----------------
__global__ __launch_bounds__(256) void k_gemm40(const float* __restrict__ h,
                                                const float* __restrict__ W0,
                                                const float* __restrict__ W1,
                                                const float* __restrict__ b,
                                                const int* __restrict__ deg_src,
                                                const int* __restrict__ maxdeg,
                                                float2* __restrict__ G02,
                                                unsigned short* __restrict__ G1f8) {
    __shared__ float2 sw0[64 * PAIRS40], sw1[64 * PAIRS40];   // 20 KB
    __shared__ float sh[32 * 64];                             // 8 KB
    int t = threadIdx.x;
    const float2* W02 = (const float2*)W0;
    const float2* W12 = (const float2*)W1;
    for (int k = t; k < 64 * PAIRS40; k += 256) { sw0[k] = W02[k]; sw1[k] = W12[k]; }
    int i0 = blockIdx.x * 32;
    const float4* h4 = (const float4*)(h + (size_t)i0 * 64);
    float4* sh4 = (float4*)sh;
    for (int k = t; k < 512; k += 256) sh4[k] = h4[k];
    __syncthreads();
    int c2 = t & 31, rg = t >> 5;
    if (c2 >= PAIRS40) return;
    float scale = 1.0f / (float)(*maxdeg);
    float2 b2 = ((const float2*)b)[c2];
    float a0x[4], a0y[4], a1x[4], a1y[4];
    #pragma unroll
    for (int p = 0; p < 4; p++) { a0x[p] = b2.x; a0y[p] = b2.y; a1x[p] = 0.f; a1y[p] = 0.f; }
    #pragma unroll
    for (int k = 0; k < 64; k++) {
        float2 w0 = sw0[k * PAIRS40 + c2];
        float2 w1 = sw1[k * PAIRS40 + c2];
        #pragma unroll
        for (int p = 0; p < 4; p++) {
            float hv = sh[(rg + 8 * p) * 64 + k];
            a0x[p] += hv * w0.x; a0y[p] += hv * w0.y;
            a1x[p] += hv * w1.x; a1y[p] += hv * w1.y;
        }
    }
    #pragma unroll
    for (int p = 0; p < 4; p++) {
        int row = i0 + rg + 8 * p;
        float nl = (float)deg_src[row] * scale - 1.0f;
        G02[row * PAIRS40 + c2] = make_float2(a0x[p] + nl * a1x[p], a0y[p] + nl * a1y[p]);
        int pk = __builtin_amdgcn_cvt_pk_fp8_f32(a1x[p], a1y[p], 0, false);
        G1f8[row * PAIRS40 + c2] = (unsigned short)(pk & 0xffff);
    }
}

// ---------------- fused SpMM + relu, 64 ch fp8, one octet (8 lanes) per node ----------------
// lane: oct = lane>>3 (node within wave), ch = lane&7 (8-channel chunk)
// No cross-lane reduction: each lane owns its 8 channels for the whole node.
__global__ __launch_bounds__(256) void k_spmm64(const float* __restrict__ G0p,
                                               const unsigned char* __restrict__ g1,
                                               const int* __restrict__ rowptr,
                                               const int* __restrict__ csr_src,
                                               const int* __restrict__ maxdeg,
                                               float* __restrict__ out) {
    int t = threadIdx.x;
    int waveId = t >> 6, lane = t & 63;
    int ch = lane & 7;
    int node = blockIdx.x * 32 + waveId * 8 + (lane >> 3);   // grid = N/32
    float scale = 1.0f / (float)(*maxdeg);
    int e0 = rowptr[node], e1 = rowptr[node + 1];
    int octbase = lane & 56;
    vf2 acc[4];
    acc[0] = 0.f; acc[1] = 0.f; acc[2] = 0.f; acc[3] = 0.f;
    for (int e = e0; e < e1; e += 8) {
        int nb = e1 - e;                         // uniform within octet
        int idx = (e + ch < e1) ? csr_src[e + ch] : 0;
        #pragma unroll
        for (int j = 0; j < 8; j++) {
            int s = __shfl(idx, octbase | j);
            if (j < nb) {
                uint2 u = ((const uint2*)(g1 + (size_t)s * 64))[ch];
                acc[0] += __builtin_amdgcn_cvt_pk_f32_fp8((int)u.x, false);
                acc[1] += __builtin_amdgcn_cvt_pk_f32_fp8((int)u.x, true);
                acc[2] += __builtin_amdgcn_cvt_pk_f32_fp8((int)u.y, false);
                acc[3] += __builtin_amdgcn_cvt_pk_f32_fp8((int)u.y, true);
            }
        }
    }
    const float4* g04 = (const float4*)(G0p + (size_t)node * 64);
    float4 gA = g04[ch * 2], gB = g04[ch * 2 + 1];
    float4 oA, oB;
    oA.x = fmaxf(gA.x - scale * acc[0].x, 0.f);
    oA.y = fmaxf(gA.y - scale * acc[0].y, 0.f);
    oA.z = fmaxf(gA.z - scale * acc[1].x, 0.f);
    oA.w = fmaxf(gA.w - scale * acc[1].y, 0.f);
    oB.x = fmaxf(gB.x - scale * acc[2].x, 0.f);
    oB.y = fmaxf(gB.y - scale * acc[2].y, 0.f);
    oB.z = fmaxf(gB.z - scale * acc[3].x, 0.f);
    oB.w = fmaxf(gB.w - scale * acc[3].y, 0.f);
    float4* o4 = (float4*)(out + (size_t)node * 64);
    o4[ch * 2] = oA;
    o4[ch * 2 + 1] = oB;
}

// ---------------- fused SpMM + log_softmax, 40 ch fp8, one octet per node ----------------
__global__ __launch_bounds__(256) void k_spmm40(const float* __restrict__ G0p,
                                               const unsigned char* __restrict__ g1,
                                               const int* __restrict__ rowptr,
                                               const int* __restrict__ csr_src,
                                               const int* __restrict__ maxdeg,
                                               float* __restrict__ out) {
    int t = threadIdx.x;
    int waveId = t >> 6, lane = t & 63;
    int ch = lane & 7;
    bool act = ch < 5;                           // 5 lanes * 8 = 40 channels
    int node = blockIdx.x * 32 + waveId * 8 + (lane >> 3);
    float scale = 1.0f / (float)(*maxdeg);
    int e0 = rowptr[node], e1 = rowptr[node + 1];
    int octbase = lane & 56;
    vf2 acc[4];
    acc[0] = 0.f; acc[1] = 0.f; acc[2] = 0.f; acc[3] = 0.f;
    for (int e = e0; e < e1; e += 8) {
        int nb = e1 - e;
        int idx = (e + ch < e1) ? csr_src[e + ch] : 0;   // all 8 lanes supply indices
        #pragma unroll
        for (int j = 0; j < 8; j++) {
            int s = __shfl(idx, octbase | j);
            if (act && j < nb) {
                uint2 u = ((const uint2*)(g1 + (size_t)s * 40))[ch];
                acc[0] += __builtin_amdgcn_cvt_pk_f32_fp8((int)u.x, false);
                acc[1] += __builtin_amdgcn_cvt_pk_f32_fp8((int)u.x, true);
                acc[2] += __builtin_amdgcn_cvt_pk_f32_fp8((int)u.y, false);
                acc[3] += __builtin_amdgcn_cvt_pk_f32_fp8((int)u.y, true);
            }
        }
    }
    // epilogue: lanes ch=0..4 of each octet hold the node's 40 values (8 each)
    float v[8];
    float m = -INFINITY;
    if (act) {
        const float4* g04 = (const float4*)(G0p + (size_t)node * 40);
        float4 gA = g04[ch * 2], gB = g04[ch * 2 + 1];
        v[0] = gA.x - scale * acc[0].x;
        v[1] = gA.y - scale * acc[0].y;
        v[2] = gA.z - scale * acc[1].x;
        v[3] = gA.w - scale * acc[1].y;
        v[4] = gB.x - scale * acc[2].x;
        v[5] = gB.y - scale * acc[2].y;
        v[6] = gB.z - scale * acc[3].x;
        v[7] = gB.w - scale * acc[3].y;
        #pragma unroll
        for (int q = 0; q < 8; q++) m = fmaxf(m, v[q]);
    }
    // octet-wide reduce (xor 1,2,4 stays inside the 8-lane group)
    m = fmaxf(m, __shfl_xor(m, 1));
    m = fmaxf(m, __shfl_xor(m, 2));
    m = fmaxf(m, __shfl_xor(m, 4));
    float s = 0.f;
    if (act) {
        #pragma unroll
        for (int q = 0; q < 8; q++) s += __expf(v[q] - m);
    }
    s += __shfl_xor(s, 1);
    s += __shfl_xor(s, 2);
    s += __shfl_xor(s, 4);
    float ls = __logf(s);
    if (act) {
        float4 oA, oB;
        oA.x = v[0] - m - ls; oA.y = v[1] - m - ls; oA.z = v[2] - m - ls; oA.w = v[3] - m - ls;
        oB.x = v[4] - m - ls; oB.y = v[5] - m - ls; oB.z = v[6] - m - ls; oB.w = v[7] - m - ls;
        float4* o4 = (float4*)(out + (size_t)node * 40);
        o4[ch * 2] = oA;
        o4[ch * 2 + 1] = oB;
    }
}

// ---------------- launch ----------------

extern "C" void kernel_launch(void* const* d_in, const int* in_sizes, int n_in,
                              void* d_out, int out_size, void* d_ws, size_t ws_size,
                              hipStream_t stream) {
    const float* x   = (const float*)d_in[0];
    const int* ei    = (const int*)d_in[1];
    const int* src   = ei;
    const int* dst   = ei + N_EDGES;
    const float* W0_0 = (const float*)d_in[2];
    const float* W1_0 = (const float*)d_in[3];
    const float* b_0  = (const float*)d_in[4];
    const float* W0_1 = (const float*)d_in[5];
    const float* W1_1 = (const float*)d_in[6];
    const float* b_1  = (const float*)d_in[7];
    const float* W0_2 = (const float*)d_in[8];
    const float* W1_2 = (const float*)d_in[9];
    const float* b_2  = (const float*)d_in[10];
    float* outp = (float*)d_out;

    // workspace layout
    int* ip = (int*)d_ws;
    int* deg_src  = ip;                      // N
    int* rowptr   = ip + 100000;             // N+1 (padded to 100032)
    int* blocksum = ip + 200064;             // 128
    int* maxdeg   = ip + 200192;             // 1 (padded to 64)
    int* csr_src  = ip + 200256;             // E
    float* fb = (float*)(ip + 1800256);
    float* hbuf = fb;                        // N*64 fp32
    float* G0   = fb + 6400000;              // region (also Hs: NC*NPAD_H=4.19M ints)
    float* G1   = fb + 12800000;             // region (G1f8: N*64B; also Hd: 16.8MB)
    int* Hs = (int*)G0;
    int* Hd = (int*)G1;
    float2* G02 = (float2*)G0;
    unsigned short* G1f8 = (unsigned short*)G1;

    (void)hipMemsetAsync(maxdeg, 0, sizeof(int), stream);

    k_hist<<<dim3(NC, NR_H, 2), 1024, 0, stream>>>(src, dst, Hs, Hd);
    k_degsrc<<<(N_NODES + 255) / 256, 256, 0, stream>>>(Hs, deg_src, maxdeg);
    k_scan1<<<SCAN_NBLK, SCAN_BLOCK, 0, stream>>>(Hd, rowptr, blocksum);
    k_scan2<<<1, SCAN_BLOCK, 0, stream>>>(rowptr, blocksum);
    k_basepos<<<(N_NODES + 255) / 256, 256, 0, stream>>>(rowptr, Hd);
    k_fill2<<<dim3(NC, NR_F), 1024, 0, stream>>>(src, dst, Hd, csr_src);

    const int GS = N_NODES / 32;   // 3125 blocks, 32 nodes/block (8 per wave)
    const int GG = N_NODES / 32;   // 3125, exact

    // layer 0: x -> hbuf
    k_gemm64<<<GG, 256, 0, stream>>>(x, W0_0, W1_0, b_0, deg_src, maxdeg, G02, G1f8);
    k_spmm64<<<GS, 256, 0, stream>>>(G0, (const unsigned char*)G1f8, rowptr, csr_src, maxdeg, hbuf);
    // layer 1: hbuf -> hbuf
    k_gemm64<<<GG, 256, 0, stream>>>(hbuf, W0_1, W1_1, b_1, deg_src, maxdeg, G02, G1f8);
    k_spmm64<<<GS, 256, 0, stream>>>(G0, (const unsigned char*)G1f8, rowptr, csr_src, maxdeg, hbuf);
    // layer 2: hbuf -> out (40 ch + log_softmax), G1 stride 40 B (4 MB, L2-resident)
    k_gemm40<<<GG, 256, 0, stream>>>(hbuf, W0_2, W1_2, b_2, deg_src, maxdeg, G02, G1f8);
    k_spmm40<<<GS, 256, 0, stream>>>(G0, (const unsigned char*)G1f8, rowptr, csr_src, maxdeg, outp);
}

// Round 10
// 352.223 us; speedup vs baseline: 1.2820x; 1.0963x over previous
//
#include <hip/hip_runtime.h>
#include <math.h>

#define N_NODES 100000
#define N_EDGES 1600000
#define OUTC 40
#define PAIRS40 20

#define NC 32                       // edge chunks
#define CHUNK (N_EDGES / NC)        // 50000 exact

// histogram pass: 16-bit packed counters, 32768 nodes/range
#define RANGE_H 32768
#define NR_H 4                      // 4*32768 = 131072 >= N
#define NPAD_H (NR_H * RANGE_H)     // 131072

// fill pass: 32-bit position counters, 16384 nodes/range
#define RANGE_F 16384
#define NR_F 7                      // 7*16384 = 114688 >= N

#define SCAN_BLOCK 1024
#define SCAN_NBLK ((N_NODES + SCAN_BLOCK - 1) / SCAN_BLOCK)   // 98

typedef float vf2 __attribute__((ext_vector_type(2)));

__device__ inline unsigned pack_bf16x2(float lo, float hi) {
    unsigned a = __float_as_uint(lo), b = __float_as_uint(hi);
    a = (a + 0x7fffu + ((a >> 16) & 1u)) >> 16;
    b = (b + 0x7fffu + ((b >> 16) & 1u)) & 0xffff0000u;
    return a | b;
}
__device__ inline float bf_lo(unsigned u) { return __uint_as_float(u << 16); }
__device__ inline float bf_hi(unsigned u) { return __uint_as_float(u & 0xffff0000u); }

// ---------------- histogram: packed 16-bit LDS counters ----------------
__global__ __launch_bounds__(1024) void k_hist(const int* __restrict__ src,
                                               const int* __restrict__ dst,
                                               int* __restrict__ Hs,
                                               int* __restrict__ Hd) {
    __shared__ unsigned h32[RANGE_H / 2];    // 64 KB, two 16-bit counters per int
    int c = blockIdx.x, r = blockIdx.y;
    const int* a = blockIdx.z ? dst : src;
    int* H = blockIdx.z ? Hd : Hs;
    for (int k = threadIdx.x; k < RANGE_H / 2; k += 1024) h32[k] = 0;
    __syncthreads();
    int r0 = r * RANGE_H;
    int e0 = c * CHUNK, e1 = e0 + CHUNK;
    for (int e = e0 + threadIdx.x; e < e1; e += 1024) {
        unsigned d = (unsigned)(a[e] - r0);
        if (d < RANGE_H) atomicAdd(&h32[d >> 1], 1u << ((d & 1) * 16));
    }
    __syncthreads();
    for (int k = threadIdx.x; k < RANGE_H; k += 1024)
        H[c * NPAD_H + r0 + k] = (int)((h32[k >> 1] >> ((k & 1) * 16)) & 0xffffu);
}

// scan1: deg_src/maxdeg from Hs; inclusive scan of deg_dst (col-sum Hd) -> rowptr[i+1]
__global__ __launch_bounds__(SCAN_BLOCK) void k_scan1(const int* __restrict__ Hs,
                                                      const int* __restrict__ Hd,
                                                      int* __restrict__ rowptr,
                                                      int* __restrict__ blocksum,
                                                      int* __restrict__ deg_src,
                                                      int* __restrict__ maxdeg) {
    __shared__ int buf[2][SCAN_BLOCK];
    int t = threadIdx.x;
    int i = blockIdx.x * SCAN_BLOCK + t;
    int vs = 0, vd = 0;
    if (i < N_NODES) {
        #pragma unroll
        for (int c = 0; c < NC; c++) { vs += Hs[c * NPAD_H + i]; vd += Hd[c * NPAD_H + i]; }
        deg_src[i] = vs;
    }
    int m = vs;
    for (int off = 32; off; off >>= 1) m = max(m, __shfl_down(m, off));
    if ((t & 63) == 0) atomicMax(maxdeg, m);
    int cur = 0;
    buf[0][t] = vd;
    __syncthreads();
    for (int off = 1; off < SCAN_BLOCK; off <<= 1) {
        int nv = buf[cur][t];
        if (t >= off) nv += buf[cur][t - off];
        buf[1 - cur][t] = nv;
        cur = 1 - cur;
        __syncthreads();
    }
    int incl = buf[cur][t];
    if (i < N_NODES) rowptr[i + 1] = incl;
    if (t == SCAN_BLOCK - 1) blocksum[blockIdx.x] = incl;
}

// finalize: rowptr += chunk offset (global scan), and Hd -> per-chunk base positions
__global__ __launch_bounds__(SCAN_BLOCK) void k_finalize(const int* __restrict__ blocksum,
                                                         int* __restrict__ rowptr,
                                                         int* __restrict__ Hd) {
    __shared__ int soff;
    int t = threadIdx.x, blk = blockIdx.x;
    if (t == 0) {
        int r = 0;
        for (int j = 0; j < blk; j++) r += blocksum[j];
        soff = r;
        if (blk == 0) rowptr[0] = 0;
    }
    __syncthreads();
    int i = blk * SCAN_BLOCK + t;
    if (i >= N_NODES) return;
    int tmp[NC];
    int s = 0;
    #pragma unroll
    for (int c = 0; c < NC; c++) { tmp[c] = Hd[c * NPAD_H + i]; s += tmp[c]; }
    int rf = rowptr[i + 1] + soff;
    rowptr[i + 1] = rf;
    int run = rf - s;
    #pragma unroll
    for (int c = 0; c < NC; c++) { Hd[c * NPAD_H + i] = run; run += tmp[c]; }
}

// counting-sort fill: LDS position counters, no global atomics
__global__ __launch_bounds__(1024) void k_fill2(const int* __restrict__ src,
                                                const int* __restrict__ dst,
                                                const int* __restrict__ basepos,
                                                int* __restrict__ csr_src) {
    __shared__ int pos[RANGE_F];
    int c = blockIdx.x, r = blockIdx.y;
    int r0 = r * RANGE_F;
    for (int k = threadIdx.x; k < RANGE_F; k += 1024) pos[k] = basepos[c * NPAD_H + r0 + k];
    __syncthreads();
    int e0 = c * CHUNK, e1 = e0 + CHUNK;
    for (int e = e0 + threadIdx.x; e < e1; e += 1024) {
        unsigned d = (unsigned)(dst[e] - r0);
        if (d < RANGE_F) {
            int s = src[e];
            int p = atomicAdd(&pos[d], 1);
            csr_src[p] = s;
        }
    }
}

// ---------------- GEMM 64->64: G0b = bf16(h@W0 + b + nl*(h@W1)); G1 = fp8(h@W1) ----------------
// input: hf (fp32) if hb==null, else hb (bf16-packed, 32 uints/row)
__global__ __launch_bounds__(256) void k_gemm64(const float* __restrict__ hf,
                                                const unsigned* __restrict__ hb,
                                                const float* __restrict__ W0,
                                                const float* __restrict__ W1,
                                                const float* __restrict__ b,
                                                const int* __restrict__ deg_src,
                                                const int* __restrict__ maxdeg,
                                                unsigned* __restrict__ G0b,
                                                unsigned short* __restrict__ G1f8) {
    __shared__ float2 sw0[64 * 32], sw1[64 * 32];   // 32 KB
    __shared__ float sh[32 * 64];                   // 8 KB
    int t = threadIdx.x;
    const float2* W02 = (const float2*)W0;
    const float2* W12 = (const float2*)W1;
    for (int k = t; k < 64 * 32; k += 256) { sw0[k] = W02[k]; sw1[k] = W12[k]; }
    int i0 = blockIdx.x * 32;    // grid exactly N/32
    if (hb) {
        const uint4* h4 = (const uint4*)(hb + (size_t)i0 * 32);   // 256 uint4
        for (int k = t; k < 256; k += 256) {
            uint4 u = h4[k];
            sh[8 * k + 0] = bf_lo(u.x); sh[8 * k + 1] = bf_hi(u.x);
            sh[8 * k + 2] = bf_lo(u.y); sh[8 * k + 3] = bf_hi(u.y);
            sh[8 * k + 4] = bf_lo(u.z); sh[8 * k + 5] = bf_hi(u.z);
            sh[8 * k + 6] = bf_lo(u.w); sh[8 * k + 7] = bf_hi(u.w);
        }
    } else {
        const float4* h4 = (const float4*)(hf + (size_t)i0 * 64);
        float4* sh4 = (float4*)sh;
        for (int k = t; k < 512; k += 256) sh4[k] = h4[k];
    }
    __syncthreads();
    int c2 = t & 31, rg = t >> 5;          // rows rg, rg+8, rg+16, rg+24
    float scale = 1.0f / (float)(*maxdeg);
    float2 b2 = ((const float2*)b)[c2];
    float a0x[4], a0y[4], a1x[4], a1y[4];
    #pragma unroll
    for (int p = 0; p < 4; p++) { a0x[p] = b2.x; a0y[p] = b2.y; a1x[p] = 0.f; a1y[p] = 0.f; }
    #pragma unroll
    for (int k = 0; k < 64; k++) {
        float2 w0 = sw0[k * 32 + c2];
        float2 w1 = sw1[k * 32 + c2];
        #pragma unroll
        for (int p = 0; p < 4; p++) {
            float hv = sh[(rg + 8 * p) * 64 + k];
            a0x[p] += hv * w0.x; a0y[p] += hv * w0.y;
            a1x[p] += hv * w1.x; a1y[p] += hv * w1.y;
        }
    }
    #pragma unroll
    for (int p = 0; p < 4; p++) {
        int row = i0 + rg + 8 * p;
        float nl = (float)deg_src[row] * scale - 1.0f;
        G0b[row * 32 + c2] = pack_bf16x2(a0x[p] + nl * a1x[p], a0y[p] + nl * a1y[p]);
        int pk = __builtin_amdgcn_cvt_pk_fp8_f32(a1x[p], a1y[p], 0, false);
        G1f8[row * 32 + c2] = (unsigned short)(pk & 0xffff);
    }
}

// ---------------- GEMM 64->40 (input always bf16 hbuf) ----------------
__global__ __launch_bounds__(256) void k_gemm40(const unsigned* __restrict__ hb,
                                                const float* __restrict__ W0,
                                                const float* __restrict__ W1,
                                                const float* __restrict__ b,
                                                const int* __restrict__ deg_src,
                                                const int* __restrict__ maxdeg,
                                                unsigned* __restrict__ G0b,
                                                unsigned short* __restrict__ G1f8) {
    __shared__ float2 sw0[64 * PAIRS40], sw1[64 * PAIRS40];   // 20 KB
    __shared__ float sh[32 * 64];                             // 8 KB
    int t = threadIdx.x;
    const float2* W02 = (const float2*)W0;
    const float2* W12 = (const float2*)W1;
    for (int k = t; k < 64 * PAIRS40; k += 256) { sw0[k] = W02[k]; sw1[k] = W12[k]; }
    int i0 = blockIdx.x * 32;
    const uint4* h4 = (const uint4*)(hb + (size_t)i0 * 32);
    for (int k = t; k < 256; k += 256) {
        uint4 u = h4[k];
        sh[8 * k + 0] = bf_lo(u.x); sh[8 * k + 1] = bf_hi(u.x);
        sh[8 * k + 2] = bf_lo(u.y); sh[8 * k + 3] = bf_hi(u.y);
        sh[8 * k + 4] = bf_lo(u.z); sh[8 * k + 5] = bf_hi(u.z);
        sh[8 * k + 6] = bf_lo(u.w); sh[8 * k + 7] = bf_hi(u.w);
    }
    __syncthreads();
    int c2 = t & 31, rg = t >> 5;
    if (c2 >= PAIRS40) return;
    float scale = 1.0f / (float)(*maxdeg);
    float2 b2 = ((const float2*)b)[c2];
    float a0x[4], a0y[4], a1x[4], a1y[4];
    #pragma unroll
    for (int p = 0; p < 4; p++) { a0x[p] = b2.x; a0y[p] = b2.y; a1x[p] = 0.f; a1y[p] = 0.f; }
    #pragma unroll
    for (int k = 0; k < 64; k++) {
        float2 w0 = sw0[k * PAIRS40 + c2];
        float2 w1 = sw1[k * PAIRS40 + c2];
        #pragma unroll
        for (int p = 0; p < 4; p++) {
            float hv = sh[(rg + 8 * p) * 64 + k];
            a0x[p] += hv * w0.x; a0y[p] += hv * w0.y;
            a1x[p] += hv * w1.x; a1y[p] += hv * w1.y;
        }
    }
    #pragma unroll
    for (int p = 0; p < 4; p++) {
        int row = i0 + rg + 8 * p;
        float nl = (float)deg_src[row] * scale - 1.0f;
        G0b[row * PAIRS40 + c2] = pack_bf16x2(a0x[p] + nl * a1x[p], a0y[p] + nl * a1y[p]);
        int pk = __builtin_amdgcn_cvt_pk_fp8_f32(a1x[p], a1y[p], 0, false);
        G1f8[row * PAIRS40 + c2] = (unsigned short)(pk & 0xffff);
    }
}

// ---------------- fused SpMM + relu, 64 ch fp8, one octet per node, bf16 out ----------------
__global__ __launch_bounds__(256) void k_spmm64(const unsigned* __restrict__ G0b,
                                               const unsigned char* __restrict__ g1,
                                               const int* __restrict__ rowptr,
                                               const int* __restrict__ csr_src,
                                               const int* __restrict__ maxdeg,
                                               unsigned* __restrict__ out) {
    int t = threadIdx.x;
    int waveId = t >> 6, lane = t & 63;
    int ch = lane & 7;
    int node = blockIdx.x * 32 + waveId * 8 + (lane >> 3);   // grid = N/32
    float scale = 1.0f / (float)(*maxdeg);
    int e0 = rowptr[node], e1 = rowptr[node + 1];
    int octbase = lane & 56;
    vf2 acc[4];
    acc[0] = 0.f; acc[1] = 0.f; acc[2] = 0.f; acc[3] = 0.f;
    int e = e0;
    int idx = (e + ch < e1) ? csr_src[e + ch] : 0;
    while (e < e1) {
        int nb = e1 - e;                         // uniform within octet
        int en = e + 8;
        int nidx = (en + ch < e1) ? csr_src[en + ch] : 0;   // prefetch next
        #pragma unroll
        for (int j = 0; j < 8; j++) {
            int s = __shfl(idx, octbase | j);
            if (j < nb) {
                uint2 u = ((const uint2*)(g1 + (size_t)s * 64))[ch];
                acc[0] += __builtin_amdgcn_cvt_pk_f32_fp8((int)u.x, false);
                acc[1] += __builtin_amdgcn_cvt_pk_f32_fp8((int)u.x, true);
                acc[2] += __builtin_amdgcn_cvt_pk_f32_fp8((int)u.y, false);
                acc[3] += __builtin_amdgcn_cvt_pk_f32_fp8((int)u.y, true);
            }
        }
        idx = nidx; e = en;
    }
    uint4 g = ((const uint4*)(G0b + (size_t)node * 32))[ch];
    uint4 o;
    o.x = pack_bf16x2(fmaxf(bf_lo(g.x) - scale * acc[0].x, 0.f),
                      fmaxf(bf_hi(g.x) - scale * acc[0].y, 0.f));
    o.y = pack_bf16x2(fmaxf(bf_lo(g.y) - scale * acc[1].x, 0.f),
                      fmaxf(bf_hi(g.y) - scale * acc[1].y, 0.f));
    o.z = pack_bf16x2(fmaxf(bf_lo(g.z) - scale * acc[2].x, 0.f),
                      fmaxf(bf_hi(g.z) - scale * acc[2].y, 0.f));
    o.w = pack_bf16x2(fmaxf(bf_lo(g.w) - scale * acc[3].x, 0.f),
                      fmaxf(bf_hi(g.w) - scale * acc[3].y, 0.f));
    ((uint4*)(out + (size_t)node * 32))[ch] = o;
}

// ---------------- fused SpMM + log_softmax, 40 ch fp8, one octet per node ----------------
__global__ __launch_bounds__(256) void k_spmm40(const unsigned* __restrict__ G0b,
                                               const unsigned char* __restrict__ g1,
                                               const int* __restrict__ rowptr,
                                               const int* __restrict__ csr_src,
                                               const int* __restrict__ maxdeg,
                                               float* __restrict__ out) {
    int t = threadIdx.x;
    int waveId = t >> 6, lane = t & 63;
    int ch = lane & 7;
    bool act = ch < 5;                           // 5 lanes * 8 = 40 channels
    int node = blockIdx.x * 32 + waveId * 8 + (lane >> 3);
    float scale = 1.0f / (float)(*maxdeg);
    int e0 = rowptr[node], e1 = rowptr[node + 1];
    int octbase = lane & 56;
    vf2 acc[4];
    acc[0] = 0.f; acc[1] = 0.f; acc[2] = 0.f; acc[3] = 0.f;
    int e = e0;
    int idx = (e + ch < e1) ? csr_src[e + ch] : 0;
    while (e < e1) {
        int nb = e1 - e;
        int en = e + 8;
        int nidx = (en + ch < e1) ? csr_src[en + ch] : 0;
        #pragma unroll
        for (int j = 0; j < 8; j++) {
            int s = __shfl(idx, octbase | j);
            if (act && j < nb) {
                uint2 u = ((const uint2*)(g1 + (size_t)s * 40))[ch];
                acc[0] += __builtin_amdgcn_cvt_pk_f32_fp8((int)u.x, false);
                acc[1] += __builtin_amdgcn_cvt_pk_f32_fp8((int)u.x, true);
                acc[2] += __builtin_amdgcn_cvt_pk_f32_fp8((int)u.y, false);
                acc[3] += __builtin_amdgcn_cvt_pk_f32_fp8((int)u.y, true);
            }
        }
        idx = nidx; e = en;
    }
    // epilogue: lanes ch=0..4 of each octet hold the node's 40 values (8 each)
    float v[8];
    float m = -INFINITY;
    if (act) {
        uint4 g = ((const uint4*)(G0b + (size_t)node * PAIRS40))[ch];   // node*20 uints, 16B-aligned
        v[0] = bf_lo(g.x) - scale * acc[0].x;
        v[1] = bf_hi(g.x) - scale * acc[0].y;
        v[2] = bf_lo(g.y) - scale * acc[1].x;
        v[3] = bf_hi(g.y) - scale * acc[1].y;
        v[4] = bf_lo(g.z) - scale * acc[2].x;
        v[5] = bf_hi(g.z) - scale * acc[2].y;
        v[6] = bf_lo(g.w) - scale * acc[3].x;
        v[7] = bf_hi(g.w) - scale * acc[3].y;
        #pragma unroll
        for (int q = 0; q < 8; q++) m = fmaxf(m, v[q]);
    }
    // octet-wide reduce (xor 1,2,4 stays inside the 8-lane group)
    m = fmaxf(m, __shfl_xor(m, 1));
    m = fmaxf(m, __shfl_xor(m, 2));
    m = fmaxf(m, __shfl_xor(m, 4));
    float s = 0.f;
    if (act) {
        #pragma unroll
        for (int q = 0; q < 8; q++) s += __expf(v[q] - m);
    }
    s += __shfl_xor(s, 1);
    s += __shfl_xor(s, 2);
    s += __shfl_xor(s, 4);
    float ls = __logf(s);
    if (act) {
        float4 oA, oB;
        oA.x = v[0] - m - ls; oA.y = v[1] - m - ls; oA.z = v[2] - m - ls; oA.w = v[3] - m - ls;
        oB.x = v[4] - m - ls; oB.y = v[5] - m - ls; oB.z = v[6] - m - ls; oB.w = v[7] - m - ls;
        float4* o4 = (float4*)(out + (size_t)node * 40);
        o4[ch * 2] = oA;
        o4[ch * 2 + 1] = oB;
    }
}

// ---------------- launch ----------------

extern "C" void kernel_launch(void* const* d_in, const int* in_sizes, int n_in,
                              void* d_out, int out_size, void* d_ws, size_t ws_size,
                              hipStream_t stream) {
    const float* x   = (const float*)d_in[0];
    const int* ei    = (const int*)d_in[1];
    const int* src   = ei;
    const int* dst   = ei + N_EDGES;
    const float* W0_0 = (const float*)d_in[2];
    const float* W1_0 = (const float*)d_in[3];
    const float* b_0  = (const float*)d_in[4];
    const float* W0_1 = (const float*)d_in[5];
    const float* W1_1 = (const float*)d_in[6];
    const float* b_1  = (const float*)d_in[7];
    const float* W0_2 = (const float*)d_in[8];
    const float* W1_2 = (const float*)d_in[9];
    const float* b_2  = (const float*)d_in[10];
    float* outp = (float*)d_out;

    // workspace layout
    int* ip = (int*)d_ws;
    int* deg_src  = ip;                      // N
    int* rowptr   = ip + 100000;             // N+1 (padded to 100032)
    int* blocksum = ip + 200064;             // 128
    int* maxdeg   = ip + 200192;             // 1 (padded to 64)
    int* csr_src  = ip + 200256;             // E
    float* fb = (float*)(ip + 1800256);
    unsigned* hbuf = (unsigned*)fb;          // N*32 uints (bf16 x2) = 12.8 MB
    float* G0   = fb + 6400000;              // region (G0b: N*32 uints; also Hs: 16.8 MB)
    float* G1   = fb + 12800000;             // region (G1f8: N*64B; also Hd: 16.8 MB)
    int* Hs = (int*)G0;
    int* Hd = (int*)G1;
    unsigned* G0b = (unsigned*)G0;
    unsigned short* G1f8 = (unsigned short*)G1;

    (void)hipMemsetAsync(maxdeg, 0, sizeof(int), stream);

    k_hist<<<dim3(NC, NR_H, 2), 1024, 0, stream>>>(src, dst, Hs, Hd);
    k_scan1<<<SCAN_NBLK, SCAN_BLOCK, 0, stream>>>(Hs, Hd, rowptr, blocksum, deg_src, maxdeg);
    k_finalize<<<SCAN_NBLK, SCAN_BLOCK, 0, stream>>>(blocksum, rowptr, Hd);
    k_fill2<<<dim3(NC, NR_F), 1024, 0, stream>>>(src, dst, Hd, csr_src);

    const int GS = N_NODES / 32;   // 3125 blocks, 32 nodes/block (8 per wave)

    // layer 0: x (fp32) -> hbuf (bf16)
    k_gemm64<<<GS, 256, 0, stream>>>(x, (const unsigned*)nullptr, W0_0, W1_0, b_0, deg_src, maxdeg, G0b, G1f8);
    k_spmm64<<<GS, 256, 0, stream>>>(G0b, (const unsigned char*)G1f8, rowptr, csr_src, maxdeg, hbuf);
    // layer 1: hbuf -> hbuf
    k_gemm64<<<GS, 256, 0, stream>>>((const float*)nullptr, hbuf, W0_1, W1_1, b_1, deg_src, maxdeg, G0b, G1f8);
    k_spmm64<<<GS, 256, 0, stream>>>(G0b, (const unsigned char*)G1f8, rowptr, csr_src, maxdeg, hbuf);
    // layer 2: hbuf -> out (40 ch + log_softmax), G1 stride 40 B (4 MB, L2-resident)
    k_gemm40<<<GS, 256, 0, stream>>>(hbuf, W0_2, W1_2, b_2, deg_src, maxdeg, G0b, G1f8);
    k_spmm40<<<GS, 256, 0, stream>>>(G0b, (const unsigned char*)G1f8, rowptr, csr_src, maxdeg, outp);
}

// Round 11
// 326.756 us; speedup vs baseline: 1.3819x; 1.0779x over previous
//
#include <hip/hip_runtime.h>
#include <math.h>

#define N_NODES 100000
#define N_EDGES 1600000
#define OUTC 40
#define PAIRS40 20

#define NC 32                       // edge chunks
#define CHUNK (N_EDGES / NC)        // 50000 exact

// histogram pass: 16-bit packed counters, 32768 nodes/range
#define RANGE_H 32768
#define NR_H 4                      // 4*32768 = 131072 >= N
#define NPAD_H (NR_H * RANGE_H)     // 131072

// fill pass: 32-bit position counters, 16384 nodes/range
#define RANGE_F 16384
#define NR_F 7                      // 7*16384 = 114688 >= N

#define SCAN_BLOCK 1024
#define SCAN_NBLK ((N_NODES + SCAN_BLOCK - 1) / SCAN_BLOCK)   // 98

typedef float vf2 __attribute__((ext_vector_type(2)));

__device__ inline unsigned pack_bf16x2(float lo, float hi) {
    unsigned a = __float_as_uint(lo), b = __float_as_uint(hi);
    a = (a + 0x7fffu + ((a >> 16) & 1u)) >> 16;
    b = (b + 0x7fffu + ((b >> 16) & 1u)) & 0xffff0000u;
    return a | b;
}
__device__ inline float bf_lo(unsigned u) { return __uint_as_float(u << 16); }
__device__ inline float bf_hi(unsigned u) { return __uint_as_float(u & 0xffff0000u); }

// ---------------- histogram: packed 16-bit LDS counters ----------------
__global__ __launch_bounds__(1024) void k_hist(const int* __restrict__ src,
                                               const int* __restrict__ dst,
                                               int* __restrict__ Hs,
                                               int* __restrict__ Hd) {
    __shared__ unsigned h32[RANGE_H / 2];    // 64 KB
    int c = blockIdx.x, r = blockIdx.y;
    const int* a = blockIdx.z ? dst : src;
    int* H = blockIdx.z ? Hd : Hs;
    for (int k = threadIdx.x; k < RANGE_H / 2; k += 1024) h32[k] = 0;
    __syncthreads();
    int r0 = r * RANGE_H;
    int e0 = c * CHUNK, e1 = e0 + CHUNK;
    for (int e = e0 + threadIdx.x; e < e1; e += 1024) {
        unsigned d = (unsigned)(a[e] - r0);
        if (d < RANGE_H) atomicAdd(&h32[d >> 1], 1u << ((d & 1) * 16));
    }
    __syncthreads();
    for (int k = threadIdx.x; k < RANGE_H; k += 1024)
        H[c * NPAD_H + r0 + k] = (int)((h32[k >> 1] >> ((k & 1) * 16)) & 0xffffu);
}

// scan1: deg_src/maxdeg from Hs; inclusive scan of PADDED deg_dst -> rowptr[i+1]
__global__ __launch_bounds__(SCAN_BLOCK) void k_scan1(const int* __restrict__ Hs,
                                                      const int* __restrict__ Hd,
                                                      int* __restrict__ rowptr,
                                                      int* __restrict__ blocksum,
                                                      int* __restrict__ deg_src,
                                                      int* __restrict__ maxdeg) {
    __shared__ int buf[2][SCAN_BLOCK];
    int t = threadIdx.x;
    int i = blockIdx.x * SCAN_BLOCK + t;
    int vs = 0, vd = 0;
    if (i < N_NODES) {
        #pragma unroll
        for (int c = 0; c < NC; c++) { vs += Hs[c * NPAD_H + i]; vd += Hd[c * NPAD_H + i]; }
        deg_src[i] = vs;
    }
    int m = vs;
    for (int off = 32; off; off >>= 1) m = max(m, __shfl_down(m, off));
    if ((t & 63) == 0) atomicMax(maxdeg, m);
    int pd = (vd + 7) & ~7;                  // pad each node's slot count to x8
    int cur = 0;
    buf[0][t] = pd;
    __syncthreads();
    for (int off = 1; off < SCAN_BLOCK; off <<= 1) {
        int nv = buf[cur][t];
        if (t >= off) nv += buf[cur][t - off];
        buf[1 - cur][t] = nv;
        cur = 1 - cur;
        __syncthreads();
    }
    int incl = buf[cur][t];
    if (i < N_NODES) rowptr[i + 1] = incl;
    if (t == SCAN_BLOCK - 1) blocksum[blockIdx.x] = incl;
}

// finalize: rowptr += chunk offset; Hd -> per-chunk base positions; write pad sentinels
__global__ __launch_bounds__(SCAN_BLOCK) void k_finalize(const int* __restrict__ blocksum,
                                                         int* __restrict__ rowptr,
                                                         int* __restrict__ Hd,
                                                         int* __restrict__ csr_src) {
    __shared__ int soff;
    int t = threadIdx.x, blk = blockIdx.x;
    if (t == 0) {
        int r = 0;
        for (int j = 0; j < blk; j++) r += blocksum[j];
        soff = r;
        if (blk == 0) rowptr[0] = 0;
    }
    __syncthreads();
    int i = blk * SCAN_BLOCK + t;
    if (i >= N_NODES) return;
    int tmp[NC];
    int s = 0;
    #pragma unroll
    for (int c = 0; c < NC; c++) { tmp[c] = Hd[c * NPAD_H + i]; s += tmp[c]; }
    int rf = rowptr[i + 1] + soff;           // padded inclusive end
    rowptr[i + 1] = rf;
    int pd = (s + 7) & ~7;
    int run = rf - pd;                       // padded base
    #pragma unroll
    for (int c = 0; c < NC; c++) { Hd[c * NPAD_H + i] = run; run += tmp[c]; }
    for (int k = run; k < rf; k++) csr_src[k] = N_NODES;   // pad slots -> zero row
}

// counting-sort fill: LDS position counters, no global atomics
__global__ __launch_bounds__(1024) void k_fill2(const int* __restrict__ src,
                                                const int* __restrict__ dst,
                                                const int* __restrict__ basepos,
                                                int* __restrict__ csr_src) {
    __shared__ int pos[RANGE_F];
    int c = blockIdx.x, r = blockIdx.y;
    int r0 = r * RANGE_F;
    for (int k = threadIdx.x; k < RANGE_F; k += 1024) pos[k] = basepos[c * NPAD_H + r0 + k];
    __syncthreads();
    int e0 = c * CHUNK, e1 = e0 + CHUNK;
    for (int e = e0 + threadIdx.x; e < e1; e += 1024) {
        unsigned d = (unsigned)(dst[e] - r0);
        if (d < RANGE_F) {
            int s = src[e];
            int p = atomicAdd(&pos[d], 1);
            csr_src[p] = s;
        }
    }
}

// ---------------- GEMM 64->64 (layer 0, fp32 x input): G0b bf16, G1 fp8; zero row N ----------------
__global__ __launch_bounds__(256) void k_gemm64(const float* __restrict__ hf,
                                                const float* __restrict__ W0,
                                                const float* __restrict__ W1,
                                                const float* __restrict__ b,
                                                const int* __restrict__ deg_src,
                                                const int* __restrict__ maxdeg,
                                                unsigned* __restrict__ G0b,
                                                unsigned short* __restrict__ G1f8) {
    __shared__ float2 sw0[64 * 32], sw1[64 * 32];   // 32 KB
    __shared__ float sh[32 * 64];                   // 8 KB
    int t = threadIdx.x;
    const float2* W02 = (const float2*)W0;
    const float2* W12 = (const float2*)W1;
    for (int k = t; k < 64 * 32; k += 256) { sw0[k] = W02[k]; sw1[k] = W12[k]; }
    int i0 = blockIdx.x * 32;
    const float4* h4 = (const float4*)(hf + (size_t)i0 * 64);
    float4* sh4 = (float4*)sh;
    for (int k = t; k < 512; k += 256) sh4[k] = h4[k];
    if (blockIdx.x == 0 && t < 16) ((unsigned*)G1f8)[N_NODES * 16 + t] = 0;   // zero row
    __syncthreads();
    int c2 = t & 31, rg = t >> 5;
    float scale = 1.0f / (float)(*maxdeg);
    float2 b2 = ((const float2*)b)[c2];
    float a0x[4], a0y[4], a1x[4], a1y[4];
    #pragma unroll
    for (int p = 0; p < 4; p++) { a0x[p] = b2.x; a0y[p] = b2.y; a1x[p] = 0.f; a1y[p] = 0.f; }
    #pragma unroll
    for (int k = 0; k < 64; k++) {
        float2 w0 = sw0[k * 32 + c2];
        float2 w1 = sw1[k * 32 + c2];
        #pragma unroll
        for (int p = 0; p < 4; p++) {
            float hv = sh[(rg + 8 * p) * 64 + k];
            a0x[p] += hv * w0.x; a0y[p] += hv * w0.y;
            a1x[p] += hv * w1.x; a1y[p] += hv * w1.y;
        }
    }
    #pragma unroll
    for (int p = 0; p < 4; p++) {
        int row = i0 + rg + 8 * p;
        float nl = (float)deg_src[row] * scale - 1.0f;
        G0b[row * 32 + c2] = pack_bf16x2(a0x[p] + nl * a1x[p], a0y[p] + nl * a1y[p]);
        int pk = __builtin_amdgcn_cvt_pk_fp8_f32(a1x[p], a1y[p], 0, false);
        G1f8[row * 32 + c2] = (unsigned short)(pk & 0xffff);
    }
}

// ---------------- fused spmm64+relu + gemm64 (next layer) ----------------
// block = 32 nodes (4 waves x 8 octets); h_new -> LDS -> gemm tile
__global__ __launch_bounds__(256) void k_fs64_g64(const unsigned* __restrict__ G0b_in,
                                                  const unsigned char* __restrict__ g1_in,
                                                  const int* __restrict__ rowptr,
                                                  const int* __restrict__ csr_src,
                                                  const int* __restrict__ deg_src,
                                                  const int* __restrict__ maxdeg,
                                                  const float* __restrict__ W0,
                                                  const float* __restrict__ W1,
                                                  const float* __restrict__ b,
                                                  unsigned* __restrict__ G0b_out,
                                                  unsigned short* __restrict__ G1f8_out) {
    __shared__ float2 sw0[64 * 32], sw1[64 * 32];   // 32 KB
    __shared__ float sh[32 * 64];                   // 8 KB
    int t = threadIdx.x;
    const float2* W02 = (const float2*)W0;
    const float2* W12 = (const float2*)W1;
    for (int k = t; k < 64 * 32; k += 256) { sw0[k] = W02[k]; sw1[k] = W12[k]; }
    // ---- spmm part ----
    int waveId = t >> 6, lane = t & 63;
    int ch = lane & 7;
    int local = waveId * 8 + (lane >> 3);
    int node = blockIdx.x * 32 + local;
    float scale = 1.0f / (float)(*maxdeg);
    int e0 = rowptr[node], e1 = rowptr[node + 1];   // multiple of 8
    int octbase = lane & 56;
    vf2 acc[4];
    acc[0] = 0.f; acc[1] = 0.f; acc[2] = 0.f; acc[3] = 0.f;
    for (int e = e0; e < e1; e += 8) {
        int idx = csr_src[e + ch];                  // always valid (padded)
        #pragma unroll
        for (int j = 0; j < 8; j++) {
            int s = __shfl(idx, octbase | j);
            uint2 u = ((const uint2*)(g1_in + (size_t)s * 64))[ch];
            acc[0] += __builtin_amdgcn_cvt_pk_f32_fp8((int)u.x, false);
            acc[1] += __builtin_amdgcn_cvt_pk_f32_fp8((int)u.x, true);
            acc[2] += __builtin_amdgcn_cvt_pk_f32_fp8((int)u.y, false);
            acc[3] += __builtin_amdgcn_cvt_pk_f32_fp8((int)u.y, true);
        }
    }
    uint4 g = ((const uint4*)(G0b_in + (size_t)node * 32))[ch];
    float* shr = sh + local * 64 + ch * 8;
    shr[0] = fmaxf(bf_lo(g.x) - scale * acc[0].x, 0.f);
    shr[1] = fmaxf(bf_hi(g.x) - scale * acc[0].y, 0.f);
    shr[2] = fmaxf(bf_lo(g.y) - scale * acc[1].x, 0.f);
    shr[3] = fmaxf(bf_hi(g.y) - scale * acc[1].y, 0.f);
    shr[4] = fmaxf(bf_lo(g.z) - scale * acc[2].x, 0.f);
    shr[5] = fmaxf(bf_hi(g.z) - scale * acc[2].y, 0.f);
    shr[6] = fmaxf(bf_lo(g.w) - scale * acc[3].x, 0.f);
    shr[7] = fmaxf(bf_hi(g.w) - scale * acc[3].y, 0.f);
    if (blockIdx.x == 0 && t < 16) ((unsigned*)G1f8_out)[N_NODES * 16 + t] = 0;  // zero row
    __syncthreads();
    // ---- gemm part ----
    int c2 = t & 31, rg = t >> 5;
    int i0 = blockIdx.x * 32;
    float2 b2 = ((const float2*)b)[c2];
    float a0x[4], a0y[4], a1x[4], a1y[4];
    #pragma unroll
    for (int p = 0; p < 4; p++) { a0x[p] = b2.x; a0y[p] = b2.y; a1x[p] = 0.f; a1y[p] = 0.f; }
    #pragma unroll
    for (int k = 0; k < 64; k++) {
        float2 w0 = sw0[k * 32 + c2];
        float2 w1 = sw1[k * 32 + c2];
        #pragma unroll
        for (int p = 0; p < 4; p++) {
            float hv = sh[(rg + 8 * p) * 64 + k];
            a0x[p] += hv * w0.x; a0y[p] += hv * w0.y;
            a1x[p] += hv * w1.x; a1y[p] += hv * w1.y;
        }
    }
    #pragma unroll
    for (int p = 0; p < 4; p++) {
        int row = i0 + rg + 8 * p;
        float nl = (float)deg_src[row] * scale - 1.0f;
        G0b_out[row * 32 + c2] = pack_bf16x2(a0x[p] + nl * a1x[p], a0y[p] + nl * a1y[p]);
        int pk = __builtin_amdgcn_cvt_pk_fp8_f32(a1x[p], a1y[p], 0, false);
        G1f8_out[row * 32 + c2] = (unsigned short)(pk & 0xffff);
    }
}

// ---------------- fused spmm64+relu + gemm40 (final layer tables) ----------------
__global__ __launch_bounds__(256) void k_fs64_g40(const unsigned* __restrict__ G0b_in,
                                                  const unsigned char* __restrict__ g1_in,
                                                  const int* __restrict__ rowptr,
                                                  const int* __restrict__ csr_src,
                                                  const int* __restrict__ deg_src,
                                                  const int* __restrict__ maxdeg,
                                                  const float* __restrict__ W0,
                                                  const float* __restrict__ W1,
                                                  const float* __restrict__ b,
                                                  unsigned* __restrict__ G0b_out,
                                                  unsigned short* __restrict__ G1f8_out) {
    __shared__ float2 sw0[64 * PAIRS40], sw1[64 * PAIRS40];   // 20 KB
    __shared__ float sh[32 * 64];                             // 8 KB
    int t = threadIdx.x;
    const float2* W02 = (const float2*)W0;
    const float2* W12 = (const float2*)W1;
    for (int k = t; k < 64 * PAIRS40; k += 256) { sw0[k] = W02[k]; sw1[k] = W12[k]; }
    // ---- spmm part ----
    int waveId = t >> 6, lane = t & 63;
    int ch = lane & 7;
    int local = waveId * 8 + (lane >> 3);
    int node = blockIdx.x * 32 + local;
    float scale = 1.0f / (float)(*maxdeg);
    int e0 = rowptr[node], e1 = rowptr[node + 1];
    int octbase = lane & 56;
    vf2 acc[4];
    acc[0] = 0.f; acc[1] = 0.f; acc[2] = 0.f; acc[3] = 0.f;
    for (int e = e0; e < e1; e += 8) {
        int idx = csr_src[e + ch];
        #pragma unroll
        for (int j = 0; j < 8; j++) {
            int s = __shfl(idx, octbase | j);
            uint2 u = ((const uint2*)(g1_in + (size_t)s * 64))[ch];
            acc[0] += __builtin_amdgcn_cvt_pk_f32_fp8((int)u.x, false);
            acc[1] += __builtin_amdgcn_cvt_pk_f32_fp8((int)u.x, true);
            acc[2] += __builtin_amdgcn_cvt_pk_f32_fp8((int)u.y, false);
            acc[3] += __builtin_amdgcn_cvt_pk_f32_fp8((int)u.y, true);
        }
    }
    uint4 g = ((const uint4*)(G0b_in + (size_t)node * 32))[ch];
    float* shr = sh + local * 64 + ch * 8;
    shr[0] = fmaxf(bf_lo(g.x) - scale * acc[0].x, 0.f);
    shr[1] = fmaxf(bf_hi(g.x) - scale * acc[0].y, 0.f);
    shr[2] = fmaxf(bf_lo(g.y) - scale * acc[1].x, 0.f);
    shr[3] = fmaxf(bf_hi(g.y) - scale * acc[1].y, 0.f);
    shr[4] = fmaxf(bf_lo(g.z) - scale * acc[2].x, 0.f);
    shr[5] = fmaxf(bf_hi(g.z) - scale * acc[2].y, 0.f);
    shr[6] = fmaxf(bf_lo(g.w) - scale * acc[3].x, 0.f);
    shr[7] = fmaxf(bf_hi(g.w) - scale * acc[3].y, 0.f);
    if (blockIdx.x == 0 && t < 10) ((unsigned*)G1f8_out)[N_NODES * 10 + t] = 0;  // zero row (40B)
    __syncthreads();
    // ---- gemm part (64 -> 40) ----
    int c2 = t & 31, rg = t >> 5;
    if (c2 >= PAIRS40) return;
    int i0 = blockIdx.x * 32;
    float2 b2 = ((const float2*)b)[c2];
    float a0x[4], a0y[4], a1x[4], a1y[4];
    #pragma unroll
    for (int p = 0; p < 4; p++) { a0x[p] = b2.x; a0y[p] = b2.y; a1x[p] = 0.f; a1y[p] = 0.f; }
    #pragma unroll
    for (int k = 0; k < 64; k++) {
        float2 w0 = sw0[k * PAIRS40 + c2];
        float2 w1 = sw1[k * PAIRS40 + c2];
        #pragma unroll
        for (int p = 0; p < 4; p++) {
            float hv = sh[(rg + 8 * p) * 64 + k];
            a0x[p] += hv * w0.x; a0y[p] += hv * w0.y;
            a1x[p] += hv * w1.x; a1y[p] += hv * w1.y;
        }
    }
    #pragma unroll
    for (int p = 0; p < 4; p++) {
        int row = i0 + rg + 8 * p;
        float nl = (float)deg_src[row] * scale - 1.0f;
        G0b_out[row * PAIRS40 + c2] = pack_bf16x2(a0x[p] + nl * a1x[p], a0y[p] + nl * a1y[p]);
        int pk = __builtin_amdgcn_cvt_pk_fp8_f32(a1x[p], a1y[p], 0, false);
        G1f8_out[row * PAIRS40 + c2] = (unsigned short)(pk & 0xffff);
    }
}

// ---------------- fused SpMM + log_softmax, 40 ch fp8, one octet per node ----------------
__global__ __launch_bounds__(256) void k_spmm40(const unsigned* __restrict__ G0b,
                                               const unsigned char* __restrict__ g1,
                                               const int* __restrict__ rowptr,
                                               const int* __restrict__ csr_src,
                                               const int* __restrict__ maxdeg,
                                               float* __restrict__ out) {
    int t = threadIdx.x;
    int waveId = t >> 6, lane = t & 63;
    int ch = lane & 7;
    bool act = ch < 5;
    int node = blockIdx.x * 32 + waveId * 8 + (lane >> 3);
    float scale = 1.0f / (float)(*maxdeg);
    int e0 = rowptr[node], e1 = rowptr[node + 1];
    int octbase = lane & 56;
    vf2 acc[4];
    acc[0] = 0.f; acc[1] = 0.f; acc[2] = 0.f; acc[3] = 0.f;
    for (int e = e0; e < e1; e += 8) {
        int idx = csr_src[e + ch];
        #pragma unroll
        for (int j = 0; j < 8; j++) {
            int s = __shfl(idx, octbase | j);
            if (act) {
                uint2 u = ((const uint2*)(g1 + (size_t)s * 40))[ch];
                acc[0] += __builtin_amdgcn_cvt_pk_f32_fp8((int)u.x, false);
                acc[1] += __builtin_amdgcn_cvt_pk_f32_fp8((int)u.x, true);
                acc[2] += __builtin_amdgcn_cvt_pk_f32_fp8((int)u.y, false);
                acc[3] += __builtin_amdgcn_cvt_pk_f32_fp8((int)u.y, true);
            }
        }
    }
    float v[8];
    float m = -INFINITY;
    if (act) {
        uint4 g = ((const uint4*)(G0b + (size_t)node * PAIRS40))[ch];
        v[0] = bf_lo(g.x) - scale * acc[0].x;
        v[1] = bf_hi(g.x) - scale * acc[0].y;
        v[2] = bf_lo(g.y) - scale * acc[1].x;
        v[3] = bf_hi(g.y) - scale * acc[1].y;
        v[4] = bf_lo(g.z) - scale * acc[2].x;
        v[5] = bf_hi(g.z) - scale * acc[2].y;
        v[6] = bf_lo(g.w) - scale * acc[3].x;
        v[7] = bf_hi(g.w) - scale * acc[3].y;
        #pragma unroll
        for (int q = 0; q < 8; q++) m = fmaxf(m, v[q]);
    }
    m = fmaxf(m, __shfl_xor(m, 1));
    m = fmaxf(m, __shfl_xor(m, 2));
    m = fmaxf(m, __shfl_xor(m, 4));
    float s = 0.f;
    if (act) {
        #pragma unroll
        for (int q = 0; q < 8; q++) s += __expf(v[q] - m);
    }
    s += __shfl_xor(s, 1);
    s += __shfl_xor(s, 2);
    s += __shfl_xor(s, 4);
    float ls = __logf(s);
    if (act) {
        float4 oA, oB;
        oA.x = v[0] - m - ls; oA.y = v[1] - m - ls; oA.z = v[2] - m - ls; oA.w = v[3] - m - ls;
        oB.x = v[4] - m - ls; oB.y = v[5] - m - ls; oB.z = v[6] - m - ls; oB.w = v[7] - m - ls;
        float4* o4 = (float4*)(out + (size_t)node * 40);
        o4[ch * 2] = oA;
        o4[ch * 2 + 1] = oB;
    }
}

// ---------------- launch ----------------

extern "C" void kernel_launch(void* const* d_in, const int* in_sizes, int n_in,
                              void* d_out, int out_size, void* d_ws, size_t ws_size,
                              hipStream_t stream) {
    const float* x   = (const float*)d_in[0];
    const int* ei    = (const int*)d_in[1];
    const int* src   = ei;
    const int* dst   = ei + N_EDGES;
    const float* W0_0 = (const float*)d_in[2];
    const float* W1_0 = (const float*)d_in[3];
    const float* b_0  = (const float*)d_in[4];
    const float* W0_1 = (const float*)d_in[5];
    const float* W1_1 = (const float*)d_in[6];
    const float* b_1  = (const float*)d_in[7];
    const float* W0_2 = (const float*)d_in[8];
    const float* W1_2 = (const float*)d_in[9];
    const float* b_2  = (const float*)d_in[10];
    float* outp = (float*)d_out;

    // workspace layout (int offsets)
    int* ip = (int*)d_ws;
    int* deg_src  = ip;                      // N
    int* rowptr   = ip + 100000;             // N+1 (padded region to 100032)
    int* blocksum = ip + 200064;             // 128
    int* maxdeg   = ip + 200192;             // 1 (pad 64)
    int* csr_src  = ip + 200256;             // padded CSR <= E + 7N = 2.3M (2.5M reserved)
    int* Hs       = ip + 2700256;            // 4.19M
    int* Hd       = ip + 6894560;            // 4.19M
    unsigned* GA0 = (unsigned*)(ip + 11088864);          // N*32 uints
    unsigned short* GA1 = (unsigned short*)(ip + 14288864); // N*32+32 ushorts
    unsigned* GB0 = (unsigned*)(ip + 15888928);          // N*32 uints
    unsigned short* GB1 = (unsigned short*)(ip + 19088928); // N*32+32 ushorts

    (void)hipMemsetAsync(maxdeg, 0, sizeof(int), stream);

    k_hist<<<dim3(NC, NR_H, 2), 1024, 0, stream>>>(src, dst, Hs, Hd);
    k_scan1<<<SCAN_NBLK, SCAN_BLOCK, 0, stream>>>(Hs, Hd, rowptr, blocksum, deg_src, maxdeg);
    k_finalize<<<SCAN_NBLK, SCAN_BLOCK, 0, stream>>>(blocksum, rowptr, Hd, csr_src);
    k_fill2<<<dim3(NC, NR_F), 1024, 0, stream>>>(src, dst, Hd, csr_src);

    const int GS = N_NODES / 32;   // 3125 blocks

    // L0: x -> GA (gemm64 layer 0)
    k_gemm64<<<GS, 256, 0, stream>>>(x, W0_0, W1_0, b_0, deg_src, maxdeg, GA0, GA1);
    // L1: spmm(GA) + relu + gemm64 layer1 -> GB
    k_fs64_g64<<<GS, 256, 0, stream>>>(GA0, (const unsigned char*)GA1, rowptr, csr_src,
                                       deg_src, maxdeg, W0_1, W1_1, b_1, GB0, GB1);
    // L2: spmm(GB) + relu + gemm40 layer2 -> GA (40-ch layout)
    k_fs64_g40<<<GS, 256, 0, stream>>>(GB0, (const unsigned char*)GB1, rowptr, csr_src,
                                       deg_src, maxdeg, W0_2, W1_2, b_2, GA0, GA1);
    // L3: spmm40 + log_softmax -> out
    k_spmm40<<<GS, 256, 0, stream>>>(GA0, (const unsigned char*)GA1, rowptr, csr_src, maxdeg, outp);
}